// Round 4
// baseline (1427.390 us; speedup 1.0000x reference)
//
#include <hip/hip_runtime.h>

#define B 4
#define C 512
#define HW 4096
#define NG 32
#define GSZ 65536   // (C/NG)*HW = 16*4096

typedef unsigned short u16;
typedef unsigned int u32;
typedef __attribute__((ext_vector_type(8))) short short8;
typedef __attribute__((ext_vector_type(4))) float f32x4;

__device__ __forceinline__ float bf2f(u16 u) {
    union { u32 i; float f; } x; x.i = ((u32)u) << 16; return x.f;
}
__device__ __forceinline__ u16 f2bf(float f) {
    union { u32 i; float f; } x; x.f = f;
    u32 r = x.i + 0x7FFF + ((x.i >> 16) & 1);   // round-nearest-even
    return (u16)(r >> 16);
}

// async global->LDS, 16B per lane. LDS dest = wave-uniform base + lane*16.
__device__ __forceinline__ void gld16(const u16* g, u16* l) {
    __builtin_amdgcn_global_load_lds(
        (const __attribute__((address_space(1))) void*)g,
        (__attribute__((address_space(3))) void*)l, 16, 0, 0);
}

// ---------------- Kernel 0: fp32 -> bf16 weight conversion ----------------
__global__ __launch_bounds__(256) void conv_kernel(
        const float* __restrict__ wq, const float* __restrict__ wk,
        const float* __restrict__ wv, const float* __restrict__ wo,
        u16* __restrict__ dst) {
    const int mat = blockIdx.y;
    const float* src = (mat == 0) ? wq : (mat == 1) ? wk : (mat == 2) ? wv : wo;
    const int idx = (blockIdx.x * 256 + threadIdx.x) * 4;
    float4 v = *(const float4*)(src + idx);
    ushort4 r;
    r.x = f2bf(v.x); r.y = f2bf(v.y); r.z = f2bf(v.z); r.w = f2bf(v.w);
    *(ushort4*)(dst + (size_t)mat * (C * C) + idx) = r;
}

// ---------------- Kernel 1: GroupNorm -> bf16 xnT (b, hw, c) ----------------
__global__ __launch_bounds__(256) void gn_kernel(
        const float* __restrict__ x, const float* __restrict__ gamma,
        const float* __restrict__ beta, u16* __restrict__ xnT) {
    const int gl = blockIdx.x;                // b*32 + g
    const int b = gl >> 5, g = gl & 31;
    const size_t base = (size_t)gl * GSZ;
    const int tid = threadIdx.x;
    float s = 0.f, s2 = 0.f;
    for (int i = tid * 4; i < GSZ; i += 1024) {
        float4 v4 = *(const float4*)(x + base + i);
        s  += v4.x + v4.y + v4.z + v4.w;
        s2 += v4.x*v4.x + v4.y*v4.y + v4.z*v4.z + v4.w*v4.w;
    }
    #pragma unroll
    for (int off = 32; off > 0; off >>= 1) {
        s  += __shfl_down(s, off, 64);
        s2 += __shfl_down(s2, off, 64);
    }
    __shared__ float rs[4], rs2[4], bc[2];
    int lane = tid & 63, wid = tid >> 6;
    if (lane == 0) { rs[wid] = s; rs2[wid] = s2; }
    __syncthreads();
    if (tid == 0) {
        float ts  = rs[0] + rs[1] + rs[2] + rs[3];
        float ts2 = rs2[0] + rs2[1] + rs2[2] + rs2[3];
        float mean = ts * (1.f / GSZ);
        float var  = ts2 * (1.f / GSZ) - mean * mean;
        bc[0] = mean; bc[1] = rsqrtf(var + 1e-6f);
    }
    __syncthreads();
    const float mean = bc[0], rstd = bc[1];
    const int c0 = g * 16;
    float gm[16], bt[16];
    #pragma unroll
    for (int c = 0; c < 16; c++) {
        float gg = gamma[c0 + c] * rstd;
        gm[c] = gg;
        bt[c] = beta[c0 + c] - mean * gg;
    }
    for (int i = tid; i < HW; i += 256) {
        u32 pk[8];
        #pragma unroll
        for (int c = 0; c < 16; c += 2) {
            float a0 = x[base + (size_t)c * HW + i] * gm[c] + bt[c];
            float a1 = x[base + (size_t)(c + 1) * HW + i] * gm[c + 1] + bt[c + 1];
            pk[c >> 1] = (u32)f2bf(a0) | ((u32)f2bf(a1) << 16);
        }
        u16* dst = xnT + ((size_t)b * HW + i) * C + c0;
        *(uint4*)dst       = make_uint4(pk[0], pk[1], pk[2], pk[3]);
        *(uint4*)(dst + 8) = make_uint4(pk[4], pk[5], pk[6], pk[7]);
    }
}

// ---------------- Kernel 2: MFMA QKV projection ----------------
// A = xnT (m=i, k=c contig), B = W (n=o, k=c contig) -> D[i,o]
// q/k: store qT/kT (b,hw,c);  v: store plain (b,c,hw)
__global__ __launch_bounds__(256) void qkv_kernel(
        const u16* __restrict__ xnT, const u16* __restrict__ wb,
        const float* __restrict__ bq, const float* __restrict__ bk,
        const float* __restrict__ bv,
        u16* __restrict__ qT, u16* __restrict__ kT, u16* __restrict__ v) {
    const int mat = blockIdx.y >> 2;
    const int oT0 = (blockIdx.y & 3) * 128;
    const int iT0 = blockIdx.x * 128;
    const int b = blockIdx.z;
    const u16* Ag = xnT + ((size_t)b * HW + iT0) * C;
    const u16* Bg = wb + (size_t)mat * C * C + (size_t)oT0 * C;
    const float* bias = (mat == 0) ? bq : (mat == 1) ? bk : bv;

    const int tid = threadIdx.x;
    const int w = tid >> 6, lane = tid & 63;
    const int qd = lane >> 4, nn = lane & 15;
    const int wm = w & 1, wn = w >> 1;

    __shared__ __align__(16) u16 As[2][128 * 32];
    __shared__ __align__(16) u16 Bs[2][128 * 32];

    f32x4 acc[4][4];
    #pragma unroll
    for (int mt = 0; mt < 4; mt++)
        #pragma unroll
        for (int nt = 0; nt < 4; nt++) acc[mt][nt] = (f32x4){0.f, 0.f, 0.f, 0.f};

    auto stage = [&](u16* dst, const u16* g, int c0) {
        #pragma unroll
        for (int p = 0; p < 2; p++) {
            int rbase = 32 * w + 16 * p;
            int row = rbase + (lane >> 2);
            gld16(g + (size_t)row * C + c0 + (((lane & 3) ^ ((row >> 1) & 3)) << 3),
                  dst + rbase * 32);
        }
    };

    stage(As[0], Ag, 0);
    stage(Bs[0], Bg, 0);

    for (int kt = 0; kt < 16; kt++) {
        const int cur = kt & 1;
        __syncthreads();
        if (kt < 15) {
            stage(As[cur ^ 1], Ag, (kt + 1) * 32);
            stage(Bs[cur ^ 1], Bg, (kt + 1) * 32);
        }
        short8 af[4], bf[4];
        #pragma unroll
        for (int mt = 0; mt < 4; mt++) {
            int row = 64 * wm + 16 * mt + nn;
            af[mt] = *(const short8*)&As[cur][row * 32 + ((qd ^ ((row >> 1) & 3)) << 3)];
        }
        #pragma unroll
        for (int nt = 0; nt < 4; nt++) {
            int row = 64 * wn + 16 * nt + nn;
            bf[nt] = *(const short8*)&Bs[cur][row * 32 + ((qd ^ ((row >> 1) & 3)) << 3)];
        }
        #pragma unroll
        for (int mt = 0; mt < 4; mt++)
            #pragma unroll
            for (int nt = 0; nt < 4; nt++)
                acc[mt][nt] = __builtin_amdgcn_mfma_f32_16x16x32_bf16(af[mt], bf[nt], acc[mt][nt], 0, 0, 0);
    }

    if (mat < 2) {
        u16* dstT = ((mat == 0) ? qT : kT) + (size_t)b * HW * C;
        #pragma unroll
        for (int nt = 0; nt < 4; nt++) {
            int o = oT0 + 64 * wn + 16 * nt + nn;
            float bb = bias[o];
            #pragma unroll
            for (int mt = 0; mt < 4; mt++) {
                int ib = iT0 + 64 * wm + 16 * mt + qd * 4;
                u16* p = dstT + (size_t)ib * C + o;
                p[0]     = f2bf(acc[mt][nt][0] + bb);
                p[C]     = f2bf(acc[mt][nt][1] + bb);
                p[2 * C] = f2bf(acc[mt][nt][2] + bb);
                p[3 * C] = f2bf(acc[mt][nt][3] + bb);
            }
        }
    } else {
        u16* vb = v + (size_t)b * C * HW;
        #pragma unroll
        for (int nt = 0; nt < 4; nt++) {
            int c = oT0 + 64 * wn + 16 * nt + nn;
            float bb = bias[c];
            #pragma unroll
            for (int mt = 0; mt < 4; mt++) {
                int ib = iT0 + 64 * wm + 16 * mt + qd * 4;
                ushort4 st;
                st.x = f2bf(acc[mt][nt][0] + bb);
                st.y = f2bf(acc[mt][nt][1] + bb);
                st.z = f2bf(acc[mt][nt][2] + bb);
                st.w = f2bf(acc[mt][nt][3] + bb);
                *(ushort4*)&vb[(size_t)c * HW + ib] = st;
            }
        }
    }
}

// ---------------- Kernel 3: MFMA flash attention, 2 j-streams / block ----------------
// Block: 512 thr = 2 groups x 4 waves; 64 q-rows. Group g handles j in [2048g, 2048g+2048).
// Within group (R3 structure): wave w: S rows [16w,16w+16); PV cols c in [128w,128w+128).
// Epilogue merges the two partial (O,m,l) streams via LDS.
__global__ __launch_bounds__(512, 2) void attn_kernel(
        const u16* __restrict__ qT, const u16* __restrict__ kT,
        const u16* __restrict__ v, u16* __restrict__ oT) {
    const int b = blockIdx.y;
    const int i0 = blockIdx.x * 64;
    const int tid = threadIdx.x;
    const int g = tid >> 8;          // j-stream group
    const int w = (tid >> 6) & 3;    // wave within group
    const int lane = tid & 63;
    const int q = lane >> 4;
    const int n = lane & 15;
    const int jbase = g * 2048;

    __shared__ __align__(16) u16 kbuf[2][2][32 * 520];   // [group][dbuf] 133,120 B
    __shared__ __align__(16) u16 pbuf[2][64 * 40];       // 10,240 B
    __shared__ __align__(16) float alphabuf[2][64];
    __shared__ __align__(16) float mf[2][64];
    __shared__ __align__(16) float lf[2][64];
    __shared__ int flagbuf[2][4];

    // persistent Q A-fragments: rows i0+16w+n, k = kstep*32 + q*8 .. +7
    short8 qf[16];
    {
        const u16* qrow = qT + ((size_t)b * HW + i0 + w * 16 + n) * C + q * 8;
        #pragma unroll
        for (int k = 0; k < 16; k++) {
            uint4 u = *(const uint4*)(qrow + k * 32);
            qf[k] = *(const short8*)&u;
        }
    }
    f32x4 oacc[4][8];
    #pragma unroll
    for (int mt = 0; mt < 4; mt++)
        #pragma unroll
        for (int nt = 0; nt < 8; nt++)
            oacc[mt][nt] = (f32x4){0.f, 0.f, 0.f, 0.f};
    float mstate[4] = {-1e30f, -1e30f, -1e30f, -1e30f};
    float lsum[4]   = {0.f, 0.f, 0.f, 0.f};

    const u16* kTb = kT + (size_t)b * HW * C;
    const u16* vb  = v  + (size_t)b * C * HW;

    // prologue: stage K chunk 0 of this group's range
    #pragma unroll
    for (int ii = 0; ii < 8; ii++) {
        int row = w * 8 + ii;
        gld16(kTb + (size_t)(jbase + row) * C + lane * 8, &kbuf[g][0][row * 520]);
    }
    const float scale = 0.04419417382415922f;   // 512^-0.5

    #pragma unroll 1
    for (int t = 0; t < 64; ++t) {
        const int cur = t & 1;
        const int j0 = jbase + t * 32;
        __syncthreads();   // A: K(cur) ready, pbuf free
        // V fragments for this chunk: direct global->register (each element read once)
        uint4 vpf[8];
        {
            const u16* vgp = vb + j0 + q * 8;
            #pragma unroll
            for (int nt = 0; nt < 8; nt++)
                vpf[nt] = *(const uint4*)(vgp + (size_t)(w * 128 + nt * 16 + n) * HW);
        }
        if (t + 1 < 64) {   // prefetch K(t+1) for this group
            const u16* gk = kTb + (size_t)(j0 + 32) * C;
            #pragma unroll
            for (int ii = 0; ii < 8; ii++) {
                int row = w * 8 + ii;
                gld16(gk + (size_t)row * C + lane * 8, &kbuf[g][cur ^ 1][row * 520]);
            }
        }
        // ---- S = Q K^T ----
        f32x4 s0 = {0.f,0.f,0.f,0.f}, s1 = {0.f,0.f,0.f,0.f};
        const u16* kb = kbuf[g][cur];
        const u16* kb0 = kb + n * 520 + q * 8;
        const u16* kb1 = kb + (16 + n) * 520 + q * 8;
        #pragma unroll
        for (int k = 0; k < 16; k++) {
            short8 bf = *(const short8*)(kb0 + k * 32);
            s0 = __builtin_amdgcn_mfma_f32_16x16x32_bf16(qf[k], bf, s0, 0, 0, 0);
        }
        #pragma unroll
        for (int k = 0; k < 16; k++) {
            short8 bf = *(const short8*)(kb1 + k * 32);
            s1 = __builtin_amdgcn_mfma_f32_16x16x32_bf16(qf[k], bf, s1, 0, 0, 0);
        }
        // ---- online softmax with 0.5 margin (exact) ----
        float alr[4];
        #pragma unroll
        for (int r = 0; r < 4; r++) {
            float v0 = s0[r] * scale, v1 = s1[r] * scale;
            float mx = fmaxf(v0, v1);
            mx = fmaxf(mx, __shfl_xor(mx, 1));
            mx = fmaxf(mx, __shfl_xor(mx, 2));
            mx = fmaxf(mx, __shfl_xor(mx, 4));
            mx = fmaxf(mx, __shfl_xor(mx, 8));
            float mold = mstate[r];
            float mnew = (mx > mold + 0.5f) ? mx : mold;
            float al = __expf(mold - mnew);      // exactly 1.0 when unchanged
            float p0 = __expf(v0 - mnew);
            float p1 = __expf(v1 - mnew);
            mstate[r] = mnew;
            lsum[r] = lsum[r] * al + (p0 + p1);
            alr[r] = al;
            pbuf[g][(w * 16 + q * 4 + r) * 40 + n]      = f2bf(p0);
            pbuf[g][(w * 16 + q * 4 + r) * 40 + 16 + n] = f2bf(p1);
        }
        int chg = (alr[0] != 1.f) | (alr[1] != 1.f) | (alr[2] != 1.f) | (alr[3] != 1.f);
        int anyc = __any(chg);
        if (lane == 0) flagbuf[g][w] = anyc;
        if (n == 0) {
            #pragma unroll
            for (int r = 0; r < 4; r++) alphabuf[g][w * 16 + q * 4 + r] = alr[r];
        }
        __syncthreads();   // B: P/alpha/flags visible
        // ---- rescale O by alpha (rare, thanks to margin) ----
        int doR = flagbuf[g][0] | flagbuf[g][1] | flagbuf[g][2] | flagbuf[g][3];
        if (doR) {
            #pragma unroll
            for (int mt = 0; mt < 4; mt++) {
                f32x4 a4 = *(const f32x4*)&alphabuf[g][mt * 16 + q * 4];
                #pragma unroll
                for (int nt = 0; nt < 8; nt++) {
                    oacc[mt][nt][0] *= a4[0];
                    oacc[mt][nt][1] *= a4[1];
                    oacc[mt][nt][2] *= a4[2];
                    oacc[mt][nt][3] *= a4[3];
                }
            }
        }
        // ---- O += P V ----
        short8 pf[4];
        #pragma unroll
        for (int mt = 0; mt < 4; mt++)
            pf[mt] = *(const short8*)&pbuf[g][(mt * 16 + n) * 40 + q * 8];
        #pragma unroll
        for (int nt = 0; nt < 8; nt++) {
            short8 vf = *(const short8*)&vpf[nt];
            #pragma unroll
            for (int mt = 0; mt < 4; mt++)
                oacc[mt][nt] = __builtin_amdgcn_mfma_f32_16x16x32_bf16(pf[mt], vf, oacc[mt][nt], 0, 0, 0);
        }
    }
    // ---- epilogue: publish per-stream (m,l); merge streams via LDS; store ----
    #pragma unroll
    for (int r = 0; r < 4; r++) {
        float l = lsum[r];
        l += __shfl_xor(l, 1);
        l += __shfl_xor(l, 2);
        l += __shfl_xor(l, 4);
        l += __shfl_xor(l, 8);
        if (n == 0) {
            lf[g][w * 16 + q * 4 + r] = l;
            mf[g][w * 16 + q * 4 + r] = mstate[r];
        }
    }
    float* obuf = (float*)&kbuf[0][0][0];   // 32 KB slice, kbuf is dead now
    #pragma unroll 1
    for (int mt = 0; mt < 4; mt++) {
        float fac[4], li[4];
        __syncthreads();
        #pragma unroll
        for (int r = 0; r < 4; r++) {
            int ro = mt * 16 + q * 4 + r;
            float m0 = mf[0][ro], m1 = mf[1][ro];
            float m12 = fmaxf(m0, m1);
            float a0 = __expf(m0 - m12), a1 = __expf(m1 - m12);
            li[r]  = 1.f / (a0 * lf[0][ro] + a1 * lf[1][ro]);
            fac[r] = (g == 0) ? a0 : a1;
        }
        if (g == 1) {
            #pragma unroll
            for (int nt = 0; nt < 8; nt++) {
                int c = w * 128 + nt * 16 + n;
                #pragma unroll
                for (int r = 0; r < 4; r++)
                    obuf[(q * 4 + r) * 512 + c] = fac[r] * oacc[mt][nt][r];
            }
        }
        __syncthreads();
        if (g == 0) {
            #pragma unroll
            for (int nt = 0; nt < 8; nt++) {
                int c = w * 128 + nt * 16 + n;
                size_t base = ((size_t)b * HW + i0 + mt * 16 + q * 4) * C + c;
                #pragma unroll
                for (int r = 0; r < 4; r++) {
                    float o = (fac[r] * oacc[mt][nt][r] + obuf[(q * 4 + r) * 512 + c]) * li[r];
                    oT[base + (size_t)r * C] = f2bf(o);
                }
            }
        }
    }
}

// ---------------- Kernel 4: MFMA output projection + bias + residual ----------------
// A = wo (m=o, k=c), B = oT (n=i, k=c) -> D[o,i] (c-major output)
__global__ __launch_bounds__(256) void proj_kernel(
        const u16* __restrict__ oT, const u16* __restrict__ wob,
        const float* __restrict__ bo, const float* __restrict__ x,
        float* __restrict__ out) {
    const int o0 = blockIdx.y * 128;
    const int i0t = blockIdx.x * 128;
    const int b = blockIdx.z;
    const u16* Ag = wob + (size_t)o0 * C;
    const u16* Bg = oT + ((size_t)b * HW + i0t) * C;

    const int tid = threadIdx.x;
    const int w = tid >> 6, lane = tid & 63;
    const int qd = lane >> 4, nn = lane & 15;
    const int wm = w & 1, wn = w >> 1;

    __shared__ __align__(16) u16 As[2][128 * 32];
    __shared__ __align__(16) u16 Bs[2][128 * 32];

    f32x4 acc[4][4];
    #pragma unroll
    for (int mt = 0; mt < 4; mt++)
        #pragma unroll
        for (int nt = 0; nt < 4; nt++) acc[mt][nt] = (f32x4){0.f, 0.f, 0.f, 0.f};

    auto stage = [&](u16* dst, const u16* g, int c0) {
        #pragma unroll
        for (int p = 0; p < 2; p++) {
            int rbase = 32 * w + 16 * p;
            int row = rbase + (lane >> 2);
            gld16(g + (size_t)row * C + c0 + (((lane & 3) ^ ((row >> 1) & 3)) << 3),
                  dst + rbase * 32);
        }
    };

    stage(As[0], Ag, 0);
    stage(Bs[0], Bg, 0);

    for (int kt = 0; kt < 16; kt++) {
        const int cur = kt & 1;
        __syncthreads();
        if (kt < 15) {
            stage(As[cur ^ 1], Ag, (kt + 1) * 32);
            stage(Bs[cur ^ 1], Bg, (kt + 1) * 32);
        }
        short8 af[4], bf[4];
        #pragma unroll
        for (int mt = 0; mt < 4; mt++) {
            int row = 64 * wm + 16 * mt + nn;
            af[mt] = *(const short8*)&As[cur][row * 32 + ((qd ^ ((row >> 1) & 3)) << 3)];
        }
        #pragma unroll
        for (int nt = 0; nt < 4; nt++) {
            int row = 64 * wn + 16 * nt + nn;
            bf[nt] = *(const short8*)&Bs[cur][row * 32 + ((qd ^ ((row >> 1) & 3)) << 3)];
        }
        #pragma unroll
        for (int mt = 0; mt < 4; mt++)
            #pragma unroll
            for (int nt = 0; nt < 4; nt++)
                acc[mt][nt] = __builtin_amdgcn_mfma_f32_16x16x32_bf16(af[mt], bf[nt], acc[mt][nt], 0, 0, 0);
    }

    #pragma unroll
    for (int mt = 0; mt < 4; mt++) {
        #pragma unroll
        for (int r = 0; r < 4; r++) {
            int o = o0 + 64 * wm + 16 * mt + qd * 4 + r;
            float bb = bo[o];
            #pragma unroll
            for (int nt = 0; nt < 4; nt++) {
                int i = i0t + 64 * wn + 16 * nt + nn;
                size_t idx = ((size_t)b * C + o) * HW + i;
                out[idx] = acc[mt][nt][r] + bb + x[idx];
            }
        }
    }
}

extern "C" void kernel_launch(void* const* d_in, const int* in_sizes, int n_in,
                              void* d_out, int out_size, void* d_ws, size_t ws_size,
                              hipStream_t stream) {
    const float* x    = (const float*)d_in[0];
    const float* gn_w = (const float*)d_in[1];
    const float* gn_b = (const float*)d_in[2];
    const float* wq   = (const float*)d_in[3];
    const float* bq   = (const float*)d_in[4];
    const float* wk   = (const float*)d_in[5];
    const float* bk   = (const float*)d_in[6];
    const float* wv   = (const float*)d_in[7];
    const float* bv   = (const float*)d_in[8];
    const float* wo   = (const float*)d_in[9];
    const float* bo   = (const float*)d_in[10];
    float* out = (float*)d_out;

    const size_t WSZ = (size_t)C * C;        // 262144
    const size_t S1  = (size_t)B * C * HW;   // 8,388,608
    u16* wb   = (u16*)d_ws;                  // [q,k,v,o] bf16 weights
    u16* wob  = wb + 3 * WSZ;
    u16* xnT  = wob + WSZ;
    u16* qT   = xnT + S1;
    u16* kT   = qT + S1;
    u16* vB   = kT + S1;
    u16* oT   = vB + S1;

    hipLaunchKernelGGL(conv_kernel, dim3(256, 4), dim3(256), 0, stream, wq, wk, wv, wo, wb);
    hipLaunchKernelGGL(gn_kernel,   dim3(B*NG), dim3(256), 0, stream, x, gn_w, gn_b, xnT);
    hipLaunchKernelGGL(qkv_kernel,  dim3(HW/128, 12, B), dim3(256), 0, stream,
                       xnT, wb, bq, bk, bv, qT, kT, vB);
    hipLaunchKernelGGL(attn_kernel, dim3(HW/64, B), dim3(512), 0, stream, qT, kT, vB, oT);
    hipLaunchKernelGGL(proj_kernel, dim3(HW/128, C/128, B), dim3(256), 0, stream, oT, wob, bo, x, out);
}

// Round 5
// 758.235 us; speedup vs baseline: 1.8825x; 1.8825x over previous
//
#include <hip/hip_runtime.h>

#define B 4
#define C 512
#define HW 4096
#define NG 32
#define GSZ 65536   // (C/NG)*HW = 16*4096

typedef unsigned short u16;
typedef unsigned int u32;
typedef __attribute__((ext_vector_type(8))) short short8;
typedef __attribute__((ext_vector_type(4))) float f32x4;

__device__ __forceinline__ float bf2f(u16 u) {
    union { u32 i; float f; } x; x.i = ((u32)u) << 16; return x.f;
}
__device__ __forceinline__ u16 f2bf(float f) {
    union { u32 i; float f; } x; x.f = f;
    u32 r = x.i + 0x7FFF + ((x.i >> 16) & 1);   // round-nearest-even
    return (u16)(r >> 16);
}

// async global->LDS, 16B per lane. LDS dest = wave-uniform base + lane*16.
__device__ __forceinline__ void gld16(const u16* g, u16* l) {
    __builtin_amdgcn_global_load_lds(
        (const __attribute__((address_space(1))) void*)g,
        (__attribute__((address_space(3))) void*)l, 16, 0, 0);
}

// ---------------- Kernel 0: fp32 -> bf16 weight conversion ----------------
__global__ __launch_bounds__(256) void conv_kernel(
        const float* __restrict__ wq, const float* __restrict__ wk,
        const float* __restrict__ wv, const float* __restrict__ wo,
        u16* __restrict__ dst) {
    const int mat = blockIdx.y;
    const float* src = (mat == 0) ? wq : (mat == 1) ? wk : (mat == 2) ? wv : wo;
    const int idx = (blockIdx.x * 256 + threadIdx.x) * 4;
    float4 v = *(const float4*)(src + idx);
    ushort4 r;
    r.x = f2bf(v.x); r.y = f2bf(v.y); r.z = f2bf(v.z); r.w = f2bf(v.w);
    *(ushort4*)(dst + (size_t)mat * (C * C) + idx) = r;
}

// ---------------- Kernel 1: GroupNorm -> bf16 xnT (b, hw, c) ----------------
__global__ __launch_bounds__(256) void gn_kernel(
        const float* __restrict__ x, const float* __restrict__ gamma,
        const float* __restrict__ beta, u16* __restrict__ xnT) {
    const int gl = blockIdx.x;                // b*32 + g
    const int b = gl >> 5, g = gl & 31;
    const size_t base = (size_t)gl * GSZ;
    const int tid = threadIdx.x;
    float s = 0.f, s2 = 0.f;
    for (int i = tid * 4; i < GSZ; i += 1024) {
        float4 v4 = *(const float4*)(x + base + i);
        s  += v4.x + v4.y + v4.z + v4.w;
        s2 += v4.x*v4.x + v4.y*v4.y + v4.z*v4.z + v4.w*v4.w;
    }
    #pragma unroll
    for (int off = 32; off > 0; off >>= 1) {
        s  += __shfl_down(s, off, 64);
        s2 += __shfl_down(s2, off, 64);
    }
    __shared__ float rs[4], rs2[4], bc[2];
    int lane = tid & 63, wid = tid >> 6;
    if (lane == 0) { rs[wid] = s; rs2[wid] = s2; }
    __syncthreads();
    if (tid == 0) {
        float ts  = rs[0] + rs[1] + rs[2] + rs[3];
        float ts2 = rs2[0] + rs2[1] + rs2[2] + rs2[3];
        float mean = ts * (1.f / GSZ);
        float var  = ts2 * (1.f / GSZ) - mean * mean;
        bc[0] = mean; bc[1] = rsqrtf(var + 1e-6f);
    }
    __syncthreads();
    const float mean = bc[0], rstd = bc[1];
    const int c0 = g * 16;
    float gm[16], bt[16];
    #pragma unroll
    for (int c = 0; c < 16; c++) {
        float gg = gamma[c0 + c] * rstd;
        gm[c] = gg;
        bt[c] = beta[c0 + c] - mean * gg;
    }
    for (int i = tid; i < HW; i += 256) {
        u32 pk[8];
        #pragma unroll
        for (int c = 0; c < 16; c += 2) {
            float a0 = x[base + (size_t)c * HW + i] * gm[c] + bt[c];
            float a1 = x[base + (size_t)(c + 1) * HW + i] * gm[c + 1] + bt[c + 1];
            pk[c >> 1] = (u32)f2bf(a0) | ((u32)f2bf(a1) << 16);
        }
        u16* dst = xnT + ((size_t)b * HW + i) * C + c0;
        *(uint4*)dst       = make_uint4(pk[0], pk[1], pk[2], pk[3]);
        *(uint4*)(dst + 8) = make_uint4(pk[4], pk[5], pk[6], pk[7]);
    }
}

// ---------------- Kernel 2: MFMA QKV projection ----------------
// A = xnT (m=i, k=c contig), B = W (n=o, k=c contig) -> D[i,o]
// q/k: store qT/kT (b,hw,c);  v: store vimg swizzled chunks (ushort4 runs)
__global__ __launch_bounds__(256) void qkv_kernel(
        const u16* __restrict__ xnT, const u16* __restrict__ wb,
        const float* __restrict__ bq, const float* __restrict__ bk,
        const float* __restrict__ bv,
        u16* __restrict__ qT, u16* __restrict__ kT, u16* __restrict__ vimg) {
    const int mat = blockIdx.y >> 2;
    const int oT0 = (blockIdx.y & 3) * 128;
    const int iT0 = blockIdx.x * 128;
    const int b = blockIdx.z;
    const u16* Ag = xnT + ((size_t)b * HW + iT0) * C;
    const u16* Bg = wb + (size_t)mat * C * C + (size_t)oT0 * C;
    const float* bias = (mat == 0) ? bq : (mat == 1) ? bk : bv;

    const int tid = threadIdx.x;
    const int w = tid >> 6, lane = tid & 63;
    const int qd = lane >> 4, nn = lane & 15;
    const int wm = w & 1, wn = w >> 1;

    __shared__ __align__(16) u16 As[2][128 * 32];
    __shared__ __align__(16) u16 Bs[2][128 * 32];

    f32x4 acc[4][4];
    #pragma unroll
    for (int mt = 0; mt < 4; mt++)
        #pragma unroll
        for (int nt = 0; nt < 4; nt++) acc[mt][nt] = (f32x4){0.f, 0.f, 0.f, 0.f};

    auto stage = [&](u16* dst, const u16* g, int c0) {
        #pragma unroll
        for (int p = 0; p < 2; p++) {
            int rbase = 32 * w + 16 * p;
            int row = rbase + (lane >> 2);
            gld16(g + (size_t)row * C + c0 + (((lane & 3) ^ ((row >> 1) & 3)) << 3),
                  dst + rbase * 32);
        }
    };

    stage(As[0], Ag, 0);
    stage(Bs[0], Bg, 0);

    for (int kt = 0; kt < 16; kt++) {
        const int cur = kt & 1;
        __syncthreads();
        if (kt < 15) {
            stage(As[cur ^ 1], Ag, (kt + 1) * 32);
            stage(Bs[cur ^ 1], Bg, (kt + 1) * 32);
        }
        short8 af[4], bf[4];
        #pragma unroll
        for (int mt = 0; mt < 4; mt++) {
            int row = 64 * wm + 16 * mt + nn;
            af[mt] = *(const short8*)&As[cur][row * 32 + ((qd ^ ((row >> 1) & 3)) << 3)];
        }
        #pragma unroll
        for (int nt = 0; nt < 4; nt++) {
            int row = 64 * wn + 16 * nt + nn;
            bf[nt] = *(const short8*)&Bs[cur][row * 32 + ((qd ^ ((row >> 1) & 3)) << 3)];
        }
        #pragma unroll
        for (int mt = 0; mt < 4; mt++)
            #pragma unroll
            for (int nt = 0; nt < 4; nt++)
                acc[mt][nt] = __builtin_amdgcn_mfma_f32_16x16x32_bf16(af[mt], bf[nt], acc[mt][nt], 0, 0, 0);
    }

    if (mat < 2) {
        u16* dstT = ((mat == 0) ? qT : kT) + (size_t)b * HW * C;
        #pragma unroll
        for (int nt = 0; nt < 4; nt++) {
            int o = oT0 + 64 * wn + 16 * nt + nn;
            float bb = bias[o];
            #pragma unroll
            for (int mt = 0; mt < 4; mt++) {
                int ib = iT0 + 64 * wm + 16 * mt + qd * 4;
                u16* p = dstT + (size_t)ib * C + o;
                p[0]     = f2bf(acc[mt][nt][0] + bb);
                p[C]     = f2bf(acc[mt][nt][1] + bb);
                p[2 * C] = f2bf(acc[mt][nt][2] + bb);
                p[3 * C] = f2bf(acc[mt][nt][3] + bb);
            }
        }
    } else {
        u16* vb = vimg + (size_t)b * 128 * 16384;
        #pragma unroll
        for (int nt = 0; nt < 4; nt++) {
            int c = oT0 + 64 * wn + 16 * nt + nn;
            float bb = bias[c];
            #pragma unroll
            for (int mt = 0; mt < 4; mt++) {
                int ib = iT0 + 64 * wm + 16 * mt + qd * 4;
                int ch = ib >> 5;
                int j0 = ib & 31;
                ushort4 st;
                st.x = f2bf(acc[mt][nt][0] + bb);
                st.y = f2bf(acc[mt][nt][1] + bb);
                st.z = f2bf(acc[mt][nt][2] + bb);
                st.w = f2bf(acc[mt][nt][3] + bb);
                *(ushort4*)&vb[(size_t)ch * 16384 + c * 32 +
                               (((j0 >> 3) ^ ((c >> 2) & 3)) << 3) + (j0 & 7)] = st;
            }
        }
    }
}

// ---------------- Kernel 3: MFMA flash attention (j-split halves) ----------------
// Block: 64 q-rows, 4 waves, 256 thr. blockIdx.z = j-half (2048 j each).
// Wave w: S rows [16w,16w+16); PV cols c in [128w,128w+128).
// Single-buffered K (XOR-swizzled) + V (vimg image); 3 barriers/chunk;
// K(t+1) staging overlaps PV. Writes normalized bf16 partial O + (m,l).
__global__ __launch_bounds__(256, 2) void attn_kernel(
        const u16* __restrict__ qT, const u16* __restrict__ kT,
        const u16* __restrict__ vimg, u16* __restrict__ Opart,
        float2* __restrict__ mlpart) {
    const int b = blockIdx.y;
    const int i0 = blockIdx.x * 64;
    const int h = blockIdx.z;          // j-half
    const int tid = threadIdx.x;
    const int w = tid >> 6;
    const int lane = tid & 63;
    const int q = lane >> 4;
    const int n = lane & 15;

    __shared__ __align__(16) u16 kbuf[32 * 512];   // 32 KB, XOR-chunk swizzle
    __shared__ __align__(16) u16 vbuf[16384];      // 32 KB, vimg image
    __shared__ __align__(16) u16 pbuf[64 * 40];    //  5 KB
    __shared__ float alphabuf[64];
    __shared__ float lbuf[64];
    __shared__ int flagbuf[4];

    // persistent Q A-fragments: rows i0+16w+n, k = kstep*32 + q*8 .. +7
    short8 qf[16];
    {
        const u16* qrow = qT + ((size_t)b * HW + i0 + w * 16 + n) * C + q * 8;
        #pragma unroll
        for (int k = 0; k < 16; k++) {
            uint4 u = *(const uint4*)(qrow + k * 32);
            qf[k] = *(const short8*)&u;
        }
    }
    f32x4 oacc[4][8];
    #pragma unroll
    for (int mt = 0; mt < 4; mt++)
        #pragma unroll
        for (int nt = 0; nt < 8; nt++)
            oacc[mt][nt] = (f32x4){0.f, 0.f, 0.f, 0.f};
    float mstate[4] = {-1e30f, -1e30f, -1e30f, -1e30f};
    float lsum[4]   = {0.f, 0.f, 0.f, 0.f};

    const u16* kTb = kT + (size_t)b * HW * C;
    const u16* vTb = vimg + (size_t)b * 128 * 16384;

    // K row j (0..31): phys 16B-chunk l holds logical chunk (l ^ (j&7))
    auto stageK = [&](int gc) {
        const u16* gk = kTb + (size_t)gc * 32 * C;
        #pragma unroll
        for (int ii = 0; ii < 8; ii++) {
            int j = w * 8 + ii;
            gld16(gk + (size_t)j * C + ((lane ^ (j & 7)) << 3), &kbuf[j * 512]);
        }
    };
    auto stageV = [&](int gc) {
        const u16* gv = vTb + (size_t)gc * 16384;
        #pragma unroll
        for (int ii = 0; ii < 8; ii++) {
            int tt = w * 8 + ii;
            gld16(gv + tt * 512 + lane * 8, &vbuf[tt * 512]);
        }
    };

    const int gc0 = h * 64;
    stageK(gc0);
    stageV(gc0);
    const float scale = 0.04419417382415922f;   // 512^-0.5

    #pragma unroll 1
    for (int t = 0; t < 64; ++t) {
        __syncthreads();   // (1) staging of chunk t complete; pbuf(t-1) consumed
        // ---- S = Q K^T ----
        f32x4 s0 = {0.f,0.f,0.f,0.f}, s1 = {0.f,0.f,0.f,0.f};
        const int sw = n & 7;                      // (16+n)&7 == n&7
        const u16* kb0 = kbuf + n * 512;
        const u16* kb1 = kbuf + (16 + n) * 512;
        #pragma unroll
        for (int kk = 0; kk < 16; kk++) {
            short8 bf = *(const short8*)&kb0[((kk * 4 + q) ^ sw) << 3];
            s0 = __builtin_amdgcn_mfma_f32_16x16x32_bf16(qf[kk], bf, s0, 0, 0, 0);
        }
        #pragma unroll
        for (int kk = 0; kk < 16; kk++) {
            short8 bf = *(const short8*)&kb1[((kk * 4 + q) ^ sw) << 3];
            s1 = __builtin_amdgcn_mfma_f32_16x16x32_bf16(qf[kk], bf, s1, 0, 0, 0);
        }
        // ---- online softmax with 0.5 margin (exact) ----
        float alr[4];
        #pragma unroll
        for (int r = 0; r < 4; r++) {
            float v0 = s0[r] * scale, v1 = s1[r] * scale;
            float mx = fmaxf(v0, v1);
            mx = fmaxf(mx, __shfl_xor(mx, 1));
            mx = fmaxf(mx, __shfl_xor(mx, 2));
            mx = fmaxf(mx, __shfl_xor(mx, 4));
            mx = fmaxf(mx, __shfl_xor(mx, 8));
            float mold = mstate[r];
            float mnew = (mx > mold + 0.5f) ? mx : mold;
            float al = __expf(mold - mnew);      // exactly 1.0 when unchanged
            float p0 = __expf(v0 - mnew);
            float p1 = __expf(v1 - mnew);
            mstate[r] = mnew;
            lsum[r] = lsum[r] * al + (p0 + p1);
            alr[r] = al;
            pbuf[(w * 16 + q * 4 + r) * 40 + n]      = f2bf(p0);
            pbuf[(w * 16 + q * 4 + r) * 40 + 16 + n] = f2bf(p1);
        }
        int chg = (alr[0] != 1.f) | (alr[1] != 1.f) | (alr[2] != 1.f) | (alr[3] != 1.f);
        int anyc = __any(chg);
        if (lane == 0) flagbuf[w] = anyc;
        if (n == 0) {
            #pragma unroll
            for (int r = 0; r < 4; r++) alphabuf[w * 16 + q * 4 + r] = alr[r];
        }
        __syncthreads();   // (2) pbuf/alpha/flags visible; kbuf reads done
        if (t < 63) stageK(gc0 + t + 1);   // overlaps PV phase
        // ---- rescale O by alpha (rare, thanks to margin) ----
        int doR = flagbuf[0] | flagbuf[1] | flagbuf[2] | flagbuf[3];
        if (doR) {
            #pragma unroll
            for (int mt = 0; mt < 4; mt++) {
                f32x4 a4 = *(const f32x4*)&alphabuf[mt * 16 + q * 4];
                #pragma unroll
                for (int nt = 0; nt < 8; nt++) {
                    oacc[mt][nt][0] *= a4[0];
                    oacc[mt][nt][1] *= a4[1];
                    oacc[mt][nt][2] *= a4[2];
                    oacc[mt][nt][3] *= a4[3];
                }
            }
        }
        // ---- O += P V ----
        short8 pf[4];
        #pragma unroll
        for (int mt = 0; mt < 4; mt++)
            pf[mt] = *(const short8*)&pbuf[(mt * 16 + n) * 40 + q * 8];
        #pragma unroll
        for (int nt = 0; nt < 8; nt++) {
            int c = w * 128 + nt * 16 + n;
            short8 vf = *(const short8*)&vbuf[c * 32 + ((q ^ ((c >> 2) & 3)) << 3)];
            #pragma unroll
            for (int mt = 0; mt < 4; mt++)
                oacc[mt][nt] = __builtin_amdgcn_mfma_f32_16x16x32_bf16(pf[mt], vf, oacc[mt][nt], 0, 0, 0);
        }
        __syncthreads();   // (3) vbuf reads done
        if (t < 63) stageV(gc0 + t + 1);
    }
    // ---- epilogue: per-row l; write normalized bf16 partial + (m,l) ----
    float lred[4];
    #pragma unroll
    for (int r = 0; r < 4; r++) {
        float l = lsum[r];
        l += __shfl_xor(l, 1);
        l += __shfl_xor(l, 2);
        l += __shfl_xor(l, 4);
        l += __shfl_xor(l, 8);
        lred[r] = l;
        if (n == 0) lbuf[w * 16 + q * 4 + r] = l;
    }
    __syncthreads();
    if (n == 0) {
        #pragma unroll
        for (int r = 0; r < 4; r++) {
            float2 e; e.x = mstate[r]; e.y = lred[r];
            mlpart[((size_t)h * B + b) * HW + i0 + w * 16 + q * 4 + r] = e;
        }
    }
    #pragma unroll
    for (int mt = 0; mt < 4; mt++) {
        f32x4 l4 = *(const f32x4*)&lbuf[mt * 16 + q * 4];
        float i0r = 1.f / l4[0], i1r = 1.f / l4[1], i2r = 1.f / l4[2], i3r = 1.f / l4[3];
        #pragma unroll
        for (int nt = 0; nt < 8; nt++) {
            int cc = w * 128 + nt * 16 + n;
            size_t base = (((size_t)h * B + b) * HW + i0 + mt * 16 + q * 4) * C + cc;
            Opart[base        ] = f2bf(oacc[mt][nt][0] * i0r);
            Opart[base +   C  ] = f2bf(oacc[mt][nt][1] * i1r);
            Opart[base + 2 * C] = f2bf(oacc[mt][nt][2] * i2r);
            Opart[base + 3 * C] = f2bf(oacc[mt][nt][3] * i3r);
        }
    }
}

// ---------------- Kernel 3b: merge the two j-half partials ----------------
__global__ __launch_bounds__(256) void merge_kernel(
        const u16* __restrict__ Opart, const float2* __restrict__ mlpart,
        u16* __restrict__ oT) {
    const int row = blockIdx.x * 4 + (threadIdx.x >> 6);   // b*HW + i
    const int lane = threadIdx.x & 63;
    float2 e0 = mlpart[row];
    float2 e1 = mlpart[(size_t)B * HW + row];
    float m = fmaxf(e0.x, e1.x);
    float a0 = __expf(e0.x - m) * e0.y;
    float a1 = __expf(e1.x - m) * e1.y;
    float inv = 1.f / (a0 + a1);
    a0 *= inv; a1 *= inv;
    size_t off = (size_t)row * C + lane * 8;
    uint4 u0 = *(const uint4*)(Opart + off);
    uint4 u1 = *(const uint4*)(Opart + (size_t)B * HW * C + off);
    const u32* p0 = (const u32*)&u0;
    const u32* p1 = (const u32*)&u1;
    u32 s[4];
    #pragma unroll
    for (int k = 0; k < 4; k++) {
        u16 lo = f2bf(a0 * bf2f((u16)p0[k]) + a1 * bf2f((u16)p1[k]));
        u16 hi = f2bf(a0 * bf2f((u16)(p0[k] >> 16)) + a1 * bf2f((u16)(p1[k] >> 16)));
        s[k] = (u32)lo | ((u32)hi << 16);
    }
    *(uint4*)(oT + off) = make_uint4(s[0], s[1], s[2], s[3]);
}

// ---------------- Kernel 4: MFMA output projection + bias + residual ----------------
// A = wo (m=o, k=c), B = oT (n=i, k=c) -> D[o,i] (c-major output)
__global__ __launch_bounds__(256) void proj_kernel(
        const u16* __restrict__ oT, const u16* __restrict__ wob,
        const float* __restrict__ bo, const float* __restrict__ x,
        float* __restrict__ out) {
    const int o0 = blockIdx.y * 128;
    const int i0t = blockIdx.x * 128;
    const int b = blockIdx.z;
    const u16* Ag = wob + (size_t)o0 * C;
    const u16* Bg = oT + ((size_t)b * HW + i0t) * C;

    const int tid = threadIdx.x;
    const int w = tid >> 6, lane = tid & 63;
    const int qd = lane >> 4, nn = lane & 15;
    const int wm = w & 1, wn = w >> 1;

    __shared__ __align__(16) u16 As[2][128 * 32];
    __shared__ __align__(16) u16 Bs[2][128 * 32];

    f32x4 acc[4][4];
    #pragma unroll
    for (int mt = 0; mt < 4; mt++)
        #pragma unroll
        for (int nt = 0; nt < 4; nt++) acc[mt][nt] = (f32x4){0.f, 0.f, 0.f, 0.f};

    auto stage = [&](u16* dst, const u16* g, int c0) {
        #pragma unroll
        for (int p = 0; p < 2; p++) {
            int rbase = 32 * w + 16 * p;
            int row = rbase + (lane >> 2);
            gld16(g + (size_t)row * C + c0 + (((lane & 3) ^ ((row >> 1) & 3)) << 3),
                  dst + rbase * 32);
        }
    };

    stage(As[0], Ag, 0);
    stage(Bs[0], Bg, 0);

    for (int kt = 0; kt < 16; kt++) {
        const int cur = kt & 1;
        __syncthreads();
        if (kt < 15) {
            stage(As[cur ^ 1], Ag, (kt + 1) * 32);
            stage(Bs[cur ^ 1], Bg, (kt + 1) * 32);
        }
        short8 af[4], bf[4];
        #pragma unroll
        for (int mt = 0; mt < 4; mt++) {
            int row = 64 * wm + 16 * mt + nn;
            af[mt] = *(const short8*)&As[cur][row * 32 + ((qd ^ ((row >> 1) & 3)) << 3)];
        }
        #pragma unroll
        for (int nt = 0; nt < 4; nt++) {
            int row = 64 * wn + 16 * nt + nn;
            bf[nt] = *(const short8*)&Bs[cur][row * 32 + ((qd ^ ((row >> 1) & 3)) << 3)];
        }
        #pragma unroll
        for (int mt = 0; mt < 4; mt++)
            #pragma unroll
            for (int nt = 0; nt < 4; nt++)
                acc[mt][nt] = __builtin_amdgcn_mfma_f32_16x16x32_bf16(af[mt], bf[nt], acc[mt][nt], 0, 0, 0);
    }

    #pragma unroll
    for (int mt = 0; mt < 4; mt++) {
        #pragma unroll
        for (int r = 0; r < 4; r++) {
            int o = o0 + 64 * wm + 16 * mt + qd * 4 + r;
            float bb = bo[o];
            #pragma unroll
            for (int nt = 0; nt < 4; nt++) {
                int i = i0t + 64 * wn + 16 * nt + nn;
                size_t idx = ((size_t)b * C + o) * HW + i;
                out[idx] = acc[mt][nt][r] + bb + x[idx];
            }
        }
    }
}

extern "C" void kernel_launch(void* const* d_in, const int* in_sizes, int n_in,
                              void* d_out, int out_size, void* d_ws, size_t ws_size,
                              hipStream_t stream) {
    const float* x    = (const float*)d_in[0];
    const float* gn_w = (const float*)d_in[1];
    const float* gn_b = (const float*)d_in[2];
    const float* wq   = (const float*)d_in[3];
    const float* bq   = (const float*)d_in[4];
    const float* wk   = (const float*)d_in[5];
    const float* bk   = (const float*)d_in[6];
    const float* wv   = (const float*)d_in[7];
    const float* bv   = (const float*)d_in[8];
    const float* wo   = (const float*)d_in[9];
    const float* bo   = (const float*)d_in[10];
    float* out = (float*)d_out;

    const size_t WSZ = (size_t)C * C;        // 262144
    const size_t S1  = (size_t)B * C * HW;   // 8,388,608
    u16* wb    = (u16*)d_ws;                 // [q,k,v,o] bf16 weights
    u16* wob   = wb + 3 * WSZ;
    u16* xnT   = wob + WSZ;                  // dead after qkv; oT aliases it
    u16* oT    = xnT;
    u16* qT    = xnT + S1;
    u16* kT    = qT + S1;
    u16* vimg  = kT + S1;
    u16* Opart = vimg + S1;                  // 2*S1 bf16 partials
    float2* ml = (float2*)(Opart + 2 * S1);  // 2*B*HW float2

    hipLaunchKernelGGL(conv_kernel,  dim3(256, 4), dim3(256), 0, stream, wq, wk, wv, wo, wb);
    hipLaunchKernelGGL(gn_kernel,    dim3(B*NG), dim3(256), 0, stream, x, gn_w, gn_b, xnT);
    hipLaunchKernelGGL(qkv_kernel,   dim3(HW/128, 12, B), dim3(256), 0, stream,
                       xnT, wb, bq, bk, bv, qT, kT, vimg);
    hipLaunchKernelGGL(attn_kernel,  dim3(HW/64, B, 2), dim3(256), 0, stream,
                       qT, kT, vimg, Opart, ml);
    hipLaunchKernelGGL(merge_kernel, dim3(B*HW/4), dim3(256), 0, stream, Opart, ml, oT);
    hipLaunchKernelGGL(proj_kernel,  dim3(HW/128, C/128, B), dim3(256), 0, stream, oT, wob, bo, x, out);
}

// Round 6
// 575.235 us; speedup vs baseline: 2.4814x; 1.3181x over previous
//
#include <hip/hip_runtime.h>

#define B 4
#define C 512
#define HW 4096
#define NG 32
#define GSZ 65536   // (C/NG)*HW = 16*4096

typedef unsigned short u16;
typedef unsigned int u32;
typedef __attribute__((ext_vector_type(8))) short short8;
typedef __attribute__((ext_vector_type(4))) float f32x4;

__device__ __forceinline__ float bf2f(u16 u) {
    union { u32 i; float f; } x; x.i = ((u32)u) << 16; return x.f;
}
__device__ __forceinline__ u16 f2bf(float f) {
    union { u32 i; float f; } x; x.f = f;
    u32 r = x.i + 0x7FFF + ((x.i >> 16) & 1);   // round-nearest-even
    return (u16)(r >> 16);
}

// async global->LDS, 16B per lane. LDS dest = wave-uniform base + lane*16.
__device__ __forceinline__ void gld16(const u16* g, u16* l) {
    __builtin_amdgcn_global_load_lds(
        (const __attribute__((address_space(1))) void*)g,
        (__attribute__((address_space(3))) void*)l, 16, 0, 0);
}

// ---------------- Kernel 0: fp32 -> bf16 weight conversion ----------------
__global__ __launch_bounds__(256) void conv_kernel(
        const float* __restrict__ wq, const float* __restrict__ wk,
        const float* __restrict__ wv, const float* __restrict__ wo,
        u16* __restrict__ dst) {
    const int mat = blockIdx.y;
    const float* src = (mat == 0) ? wq : (mat == 1) ? wk : (mat == 2) ? wv : wo;
    const int idx = (blockIdx.x * 256 + threadIdx.x) * 4;
    float4 v = *(const float4*)(src + idx);
    ushort4 r;
    r.x = f2bf(v.x); r.y = f2bf(v.y); r.z = f2bf(v.z); r.w = f2bf(v.w);
    *(ushort4*)(dst + (size_t)mat * (C * C) + idx) = r;
}

// ---------------- Kernel 1: GroupNorm -> bf16 xnT (b, hw, c) ----------------
__global__ __launch_bounds__(256) void gn_kernel(
        const float* __restrict__ x, const float* __restrict__ gamma,
        const float* __restrict__ beta, u16* __restrict__ xnT) {
    const int gl = blockIdx.x;                // b*32 + g
    const int b = gl >> 5, g = gl & 31;
    const size_t base = (size_t)gl * GSZ;
    const int tid = threadIdx.x;
    float s = 0.f, s2 = 0.f;
    for (int i = tid * 4; i < GSZ; i += 1024) {
        float4 v4 = *(const float4*)(x + base + i);
        s  += v4.x + v4.y + v4.z + v4.w;
        s2 += v4.x*v4.x + v4.y*v4.y + v4.z*v4.z + v4.w*v4.w;
    }
    #pragma unroll
    for (int off = 32; off > 0; off >>= 1) {
        s  += __shfl_down(s, off, 64);
        s2 += __shfl_down(s2, off, 64);
    }
    __shared__ float rs[4], rs2[4], bc[2];
    int lane = tid & 63, wid = tid >> 6;
    if (lane == 0) { rs[wid] = s; rs2[wid] = s2; }
    __syncthreads();
    if (tid == 0) {
        float ts  = rs[0] + rs[1] + rs[2] + rs[3];
        float ts2 = rs2[0] + rs2[1] + rs2[2] + rs2[3];
        float mean = ts * (1.f / GSZ);
        float var  = ts2 * (1.f / GSZ) - mean * mean;
        bc[0] = mean; bc[1] = rsqrtf(var + 1e-6f);
    }
    __syncthreads();
    const float mean = bc[0], rstd = bc[1];
    const int c0 = g * 16;
    float gm[16], bt[16];
    #pragma unroll
    for (int c = 0; c < 16; c++) {
        float gg = gamma[c0 + c] * rstd;
        gm[c] = gg;
        bt[c] = beta[c0 + c] - mean * gg;
    }
    for (int i = tid; i < HW; i += 256) {
        u32 pk[8];
        #pragma unroll
        for (int c = 0; c < 16; c += 2) {
            float a0 = x[base + (size_t)c * HW + i] * gm[c] + bt[c];
            float a1 = x[base + (size_t)(c + 1) * HW + i] * gm[c + 1] + bt[c + 1];
            pk[c >> 1] = (u32)f2bf(a0) | ((u32)f2bf(a1) << 16);
        }
        u16* dst = xnT + ((size_t)b * HW + i) * C + c0;
        *(uint4*)dst       = make_uint4(pk[0], pk[1], pk[2], pk[3]);
        *(uint4*)(dst + 8) = make_uint4(pk[4], pk[5], pk[6], pk[7]);
    }
}

// ---------------- Kernel 2: MFMA QKV projection ----------------
// A = xnT (m=i, k=c contig), B = W (n=o, k=c contig) -> D[i,o]
// q/k: store qT/kT (b,hw,c);  v: store vimg swizzled chunks (ushort4 runs)
__global__ __launch_bounds__(256) void qkv_kernel(
        const u16* __restrict__ xnT, const u16* __restrict__ wb,
        const float* __restrict__ bq, const float* __restrict__ bk,
        const float* __restrict__ bv,
        u16* __restrict__ qT, u16* __restrict__ kT, u16* __restrict__ vimg) {
    const int mat = blockIdx.y >> 2;
    const int oT0 = (blockIdx.y & 3) * 128;
    const int iT0 = blockIdx.x * 128;
    const int b = blockIdx.z;
    const u16* Ag = xnT + ((size_t)b * HW + iT0) * C;
    const u16* Bg = wb + (size_t)mat * C * C + (size_t)oT0 * C;
    const float* bias = (mat == 0) ? bq : (mat == 1) ? bk : bv;

    const int tid = threadIdx.x;
    const int w = tid >> 6, lane = tid & 63;
    const int qd = lane >> 4, nn = lane & 15;
    const int wm = w & 1, wn = w >> 1;

    __shared__ __align__(16) u16 As[2][128 * 32];
    __shared__ __align__(16) u16 Bs[2][128 * 32];

    f32x4 acc[4][4];
    #pragma unroll
    for (int mt = 0; mt < 4; mt++)
        #pragma unroll
        for (int nt = 0; nt < 4; nt++) acc[mt][nt] = (f32x4){0.f, 0.f, 0.f, 0.f};

    auto stage = [&](u16* dst, const u16* g, int c0) {
        #pragma unroll
        for (int p = 0; p < 2; p++) {
            int rbase = 32 * w + 16 * p;
            int row = rbase + (lane >> 2);
            gld16(g + (size_t)row * C + c0 + (((lane & 3) ^ ((row >> 1) & 3)) << 3),
                  dst + rbase * 32);
        }
    };

    stage(As[0], Ag, 0);
    stage(Bs[0], Bg, 0);

    for (int kt = 0; kt < 16; kt++) {
        const int cur = kt & 1;
        __syncthreads();
        if (kt < 15) {
            stage(As[cur ^ 1], Ag, (kt + 1) * 32);
            stage(Bs[cur ^ 1], Bg, (kt + 1) * 32);
        }
        short8 af[4], bf[4];
        #pragma unroll
        for (int mt = 0; mt < 4; mt++) {
            int row = 64 * wm + 16 * mt + nn;
            af[mt] = *(const short8*)&As[cur][row * 32 + ((qd ^ ((row >> 1) & 3)) << 3)];
        }
        #pragma unroll
        for (int nt = 0; nt < 4; nt++) {
            int row = 64 * wn + 16 * nt + nn;
            bf[nt] = *(const short8*)&Bs[cur][row * 32 + ((qd ^ ((row >> 1) & 3)) << 3)];
        }
        #pragma unroll
        for (int mt = 0; mt < 4; mt++)
            #pragma unroll
            for (int nt = 0; nt < 4; nt++)
                acc[mt][nt] = __builtin_amdgcn_mfma_f32_16x16x32_bf16(af[mt], bf[nt], acc[mt][nt], 0, 0, 0);
    }

    if (mat < 2) {
        u16* dstT = ((mat == 0) ? qT : kT) + (size_t)b * HW * C;
        #pragma unroll
        for (int nt = 0; nt < 4; nt++) {
            int o = oT0 + 64 * wn + 16 * nt + nn;
            float bb = bias[o];
            #pragma unroll
            for (int mt = 0; mt < 4; mt++) {
                int ib = iT0 + 64 * wm + 16 * mt + qd * 4;
                u16* p = dstT + (size_t)ib * C + o;
                p[0]     = f2bf(acc[mt][nt][0] + bb);
                p[C]     = f2bf(acc[mt][nt][1] + bb);
                p[2 * C] = f2bf(acc[mt][nt][2] + bb);
                p[3 * C] = f2bf(acc[mt][nt][3] + bb);
            }
        }
    } else {
        u16* vb = vimg + (size_t)b * 128 * 16384;
        #pragma unroll
        for (int nt = 0; nt < 4; nt++) {
            int c = oT0 + 64 * wn + 16 * nt + nn;
            float bb = bias[c];
            #pragma unroll
            for (int mt = 0; mt < 4; mt++) {
                int ib = iT0 + 64 * wm + 16 * mt + qd * 4;
                int ch = ib >> 5;
                int j0 = ib & 31;
                ushort4 st;
                st.x = f2bf(acc[mt][nt][0] + bb);
                st.y = f2bf(acc[mt][nt][1] + bb);
                st.z = f2bf(acc[mt][nt][2] + bb);
                st.w = f2bf(acc[mt][nt][3] + bb);
                *(ushort4*)&vb[(size_t)ch * 16384 + c * 32 +
                               (((j0 >> 3) ^ ((c >> 2) & 3)) << 3) + (j0 & 7)] = st;
            }
        }
    }
}

// ---------------- Kernel 3: MFMA flash attention (32-row tiles, j-split halves) ----------------
// Block: 32 q-rows, 4 waves, 256 thr. blockIdx.z = j-half (2048 j each).
// Wave w = (row-half rw = w&1) x (j-quadrant jh = w>>1) for the 32x32 S tile.
// PV: wave w owns cols [128w, 128w+128) for all 32 rows -> oacc 64 f32/lane.
// Single-buffered K (XOR-swizzled) + V (vimg image); 3 barriers/chunk.
__global__ __launch_bounds__(256, 2) void attn_kernel(
        const u16* __restrict__ qT, const u16* __restrict__ kT,
        const u16* __restrict__ vimg, u16* __restrict__ Opart,
        float2* __restrict__ mlpart) {
    const int b = blockIdx.y;
    const int i0 = blockIdx.x * 32;
    const int h = blockIdx.z;          // j-half
    const int tid = threadIdx.x;
    const int w = tid >> 6;
    const int lane = tid & 63;
    const int q = lane >> 4;
    const int n = lane & 15;
    const int rw = w & 1;              // S row-half
    const int jh = w >> 1;             // S j-quadrant

    __shared__ __align__(16) u16 kbuf[32 * 512];   // 32 KB, XOR-chunk swizzle
    __shared__ __align__(16) u16 vbuf[16384];      // 32 KB, vimg image
    __shared__ __align__(16) u16 pbuf[32 * 40];    // 2.5 KB
    __shared__ __align__(16) float maxbuf[2][32];
    __shared__ __align__(16) float alphabuf[32];
    __shared__ __align__(16) float lpart[2][32];
    __shared__ int flagbuf[4];

    // persistent Q A-fragments: rows i0 + rw*16 + n, k = kk*32 + q*8 .. +7
    short8 qf[16];
    {
        const u16* qrow = qT + ((size_t)b * HW + i0 + rw * 16 + n) * C + q * 8;
        #pragma unroll
        for (int k = 0; k < 16; k++) {
            uint4 u = *(const uint4*)(qrow + k * 32);
            qf[k] = *(const short8*)&u;
        }
    }
    f32x4 oacc[2][8];
    #pragma unroll
    for (int mt = 0; mt < 2; mt++)
        #pragma unroll
        for (int nt = 0; nt < 8; nt++)
            oacc[mt][nt] = (f32x4){0.f, 0.f, 0.f, 0.f};
    float mstate[4] = {-1e30f, -1e30f, -1e30f, -1e30f};
    float lsum[4]   = {0.f, 0.f, 0.f, 0.f};

    const u16* kTb = kT + (size_t)b * HW * C;
    const u16* vTb = vimg + (size_t)b * 128 * 16384;

    // K row j (0..31): phys 16B-chunk l holds logical chunk (l ^ (j&7))
    auto stageK = [&](int gc) {
        const u16* gk = kTb + (size_t)gc * 32 * C;
        #pragma unroll
        for (int ii = 0; ii < 8; ii++) {
            int j = w * 8 + ii;
            gld16(gk + (size_t)j * C + ((lane ^ (j & 7)) << 3), &kbuf[j * 512]);
        }
    };
    auto stageV = [&](int gc) {
        const u16* gv = vTb + (size_t)gc * 16384;
        #pragma unroll
        for (int ii = 0; ii < 8; ii++) {
            int tt = w * 8 + ii;
            gld16(gv + tt * 512 + lane * 8, &vbuf[tt * 512]);
        }
    };

    const int gc0 = h * 64;
    stageK(gc0);
    stageV(gc0);
    const float scale = 0.04419417382415922f;   // 512^-0.5
    __syncthreads();   // chunk 0 staged

    #pragma unroll 1
    for (int t = 0; t < 64; ++t) {
        // ---- S quadrant = Q(rows rw*16..) K^T(j = jh*16 + n) ----
        f32x4 s = {0.f, 0.f, 0.f, 0.f};
        {
            const int sw = n & 7;
            const u16* kb = kbuf + (jh * 16 + n) * 512;
            #pragma unroll
            for (int kk = 0; kk < 16; kk++) {
                short8 bf = *(const short8*)&kb[((kk * 4 + q) ^ sw) << 3];
                s = __builtin_amdgcn_mfma_f32_16x16x32_bf16(qf[kk], bf, s, 0, 0, 0);
            }
        }
        // per-quadrant row maxima -> LDS
        float sv[4], mqx[4];
        #pragma unroll
        for (int r = 0; r < 4; r++) {
            float v0 = s[r] * scale;
            sv[r] = v0;
            float mx = v0;
            mx = fmaxf(mx, __shfl_xor(mx, 1));
            mx = fmaxf(mx, __shfl_xor(mx, 2));
            mx = fmaxf(mx, __shfl_xor(mx, 4));
            mx = fmaxf(mx, __shfl_xor(mx, 8));
            mqx[r] = mx;
        }
        if (n == 0) {
            #pragma unroll
            for (int r = 0; r < 4; r++) maxbuf[jh][rw * 16 + q * 4 + r] = mqx[r];
        }
        __syncthreads();   // B1: maxbuf visible; kbuf consumed
        if (t < 63) stageK(gc0 + t + 1);
        // ---- online softmax with 0.5 margin (exact; both jh waves agree) ----
        float alr[4];
        #pragma unroll
        for (int r = 0; r < 4; r++) {
            int row = rw * 16 + q * 4 + r;
            float mx = fmaxf(maxbuf[0][row], maxbuf[1][row]);
            float mold = mstate[r];
            float mnew = (mx > mold + 0.5f) ? mx : mold;
            float al = __expf(mold - mnew);      // exactly 1.0 when unchanged
            float p = __expf(sv[r] - mnew);
            mstate[r] = mnew;
            lsum[r] = lsum[r] * al + p;
            alr[r] = al;
            pbuf[row * 40 + jh * 16 + n] = f2bf(p);
        }
        int chg = (alr[0] != 1.f) | (alr[1] != 1.f) | (alr[2] != 1.f) | (alr[3] != 1.f);
        int anyc = __any(chg);
        if (lane == 0) flagbuf[w] = anyc;
        if (jh == 0 && n == 0) {
            #pragma unroll
            for (int r = 0; r < 4; r++) alphabuf[rw * 16 + q * 4 + r] = alr[r];
        }
        __syncthreads();   // B2: pbuf/alpha/flags visible; staged K drained
        // ---- rescale O by alpha (rare, thanks to margin) ----
        int doR = flagbuf[0] | flagbuf[1] | flagbuf[2] | flagbuf[3];
        if (doR) {
            #pragma unroll
            for (int mt = 0; mt < 2; mt++) {
                f32x4 a4 = *(const f32x4*)&alphabuf[mt * 16 + q * 4];
                #pragma unroll
                for (int nt = 0; nt < 8; nt++) {
                    oacc[mt][nt][0] *= a4[0];
                    oacc[mt][nt][1] *= a4[1];
                    oacc[mt][nt][2] *= a4[2];
                    oacc[mt][nt][3] *= a4[3];
                }
            }
        }
        // ---- O += P V  (wave w: cols 128w..128w+127, all 32 rows) ----
        short8 pf[2];
        #pragma unroll
        for (int mt = 0; mt < 2; mt++)
            pf[mt] = *(const short8*)&pbuf[(mt * 16 + n) * 40 + q * 8];
        #pragma unroll
        for (int nt = 0; nt < 8; nt++) {
            int c = w * 128 + nt * 16 + n;
            short8 vf = *(const short8*)&vbuf[c * 32 + ((q ^ ((c >> 2) & 3)) << 3)];
            #pragma unroll
            for (int mt = 0; mt < 2; mt++)
                oacc[mt][nt] = __builtin_amdgcn_mfma_f32_16x16x32_bf16(pf[mt], vf, oacc[mt][nt], 0, 0, 0);
        }
        __syncthreads();   // B3: vbuf consumed
        if (t < 63) stageV(gc0 + t + 1);
    }
    // ---- epilogue: per-(row,jh) partial l -> LDS; merge; write partials ----
    #pragma unroll
    for (int r = 0; r < 4; r++) {
        float l = lsum[r];
        l += __shfl_xor(l, 1);
        l += __shfl_xor(l, 2);
        l += __shfl_xor(l, 4);
        l += __shfl_xor(l, 8);
        if (n == 0) lpart[jh][rw * 16 + q * 4 + r] = l;
    }
    __syncthreads();
    if (jh == 0 && n == 0) {
        #pragma unroll
        for (int r = 0; r < 4; r++) {
            int row = rw * 16 + q * 4 + r;
            float2 e; e.x = mstate[r]; e.y = lpart[0][row] + lpart[1][row];
            mlpart[((size_t)h * B + b) * HW + i0 + row] = e;
        }
    }
    #pragma unroll
    for (int mt = 0; mt < 2; mt++) {
        float inv[4];
        #pragma unroll
        for (int r = 0; r < 4; r++) {
            int row = mt * 16 + q * 4 + r;
            inv[r] = 1.f / (lpart[0][row] + lpart[1][row]);
        }
        #pragma unroll
        for (int nt = 0; nt < 8; nt++) {
            int cc = w * 128 + nt * 16 + n;
            size_t base = (((size_t)h * B + b) * HW + i0 + mt * 16 + q * 4) * C + cc;
            Opart[base        ] = f2bf(oacc[mt][nt][0] * inv[0]);
            Opart[base +   C  ] = f2bf(oacc[mt][nt][1] * inv[1]);
            Opart[base + 2 * C] = f2bf(oacc[mt][nt][2] * inv[2]);
            Opart[base + 3 * C] = f2bf(oacc[mt][nt][3] * inv[3]);
        }
    }
}

// ---------------- Kernel 3b: merge the two j-half partials ----------------
__global__ __launch_bounds__(256) void merge_kernel(
        const u16* __restrict__ Opart, const float2* __restrict__ mlpart,
        u16* __restrict__ oT) {
    const int row = blockIdx.x * 4 + (threadIdx.x >> 6);   // b*HW + i
    const int lane = threadIdx.x & 63;
    float2 e0 = mlpart[row];
    float2 e1 = mlpart[(size_t)B * HW + row];
    float m = fmaxf(e0.x, e1.x);
    float a0 = __expf(e0.x - m) * e0.y;
    float a1 = __expf(e1.x - m) * e1.y;
    float inv = 1.f / (a0 + a1);
    a0 *= inv; a1 *= inv;
    size_t off = (size_t)row * C + lane * 8;
    uint4 u0 = *(const uint4*)(Opart + off);
    uint4 u1 = *(const uint4*)(Opart + (size_t)B * HW * C + off);
    const u32* p0 = (const u32*)&u0;
    const u32* p1 = (const u32*)&u1;
    u32 s[4];
    #pragma unroll
    for (int k = 0; k < 4; k++) {
        u16 lo = f2bf(a0 * bf2f((u16)p0[k]) + a1 * bf2f((u16)p1[k]));
        u16 hi = f2bf(a0 * bf2f((u16)(p0[k] >> 16)) + a1 * bf2f((u16)(p1[k] >> 16)));
        s[k] = (u32)lo | ((u32)hi << 16);
    }
    *(uint4*)(oT + off) = make_uint4(s[0], s[1], s[2], s[3]);
}

// ---------------- Kernel 4: MFMA output projection + bias + residual ----------------
// A = wo (m=o, k=c), B = oT (n=i, k=c) -> D[o,i] (c-major output)
__global__ __launch_bounds__(256) void proj_kernel(
        const u16* __restrict__ oT, const u16* __restrict__ wob,
        const float* __restrict__ bo, const float* __restrict__ x,
        float* __restrict__ out) {
    const int o0 = blockIdx.y * 128;
    const int i0t = blockIdx.x * 128;
    const int b = blockIdx.z;
    const u16* Ag = wob + (size_t)o0 * C;
    const u16* Bg = oT + ((size_t)b * HW + i0t) * C;

    const int tid = threadIdx.x;
    const int w = tid >> 6, lane = tid & 63;
    const int qd = lane >> 4, nn = lane & 15;
    const int wm = w & 1, wn = w >> 1;

    __shared__ __align__(16) u16 As[2][128 * 32];
    __shared__ __align__(16) u16 Bs[2][128 * 32];

    f32x4 acc[4][4];
    #pragma unroll
    for (int mt = 0; mt < 4; mt++)
        #pragma unroll
        for (int nt = 0; nt < 4; nt++) acc[mt][nt] = (f32x4){0.f, 0.f, 0.f, 0.f};

    auto stage = [&](u16* dst, const u16* g, int c0) {
        #pragma unroll
        for (int p = 0; p < 2; p++) {
            int rbase = 32 * w + 16 * p;
            int row = rbase + (lane >> 2);
            gld16(g + (size_t)row * C + c0 + (((lane & 3) ^ ((row >> 1) & 3)) << 3),
                  dst + rbase * 32);
        }
    };

    stage(As[0], Ag, 0);
    stage(Bs[0], Bg, 0);

    for (int kt = 0; kt < 16; kt++) {
        const int cur = kt & 1;
        __syncthreads();
        if (kt < 15) {
            stage(As[cur ^ 1], Ag, (kt + 1) * 32);
            stage(Bs[cur ^ 1], Bg, (kt + 1) * 32);
        }
        short8 af[4], bf[4];
        #pragma unroll
        for (int mt = 0; mt < 4; mt++) {
            int row = 64 * wm + 16 * mt + nn;
            af[mt] = *(const short8*)&As[cur][row * 32 + ((qd ^ ((row >> 1) & 3)) << 3)];
        }
        #pragma unroll
        for (int nt = 0; nt < 4; nt++) {
            int row = 64 * wn + 16 * nt + nn;
            bf[nt] = *(const short8*)&Bs[cur][row * 32 + ((qd ^ ((row >> 1) & 3)) << 3)];
        }
        #pragma unroll
        for (int mt = 0; mt < 4; mt++)
            #pragma unroll
            for (int nt = 0; nt < 4; nt++)
                acc[mt][nt] = __builtin_amdgcn_mfma_f32_16x16x32_bf16(af[mt], bf[nt], acc[mt][nt], 0, 0, 0);
    }

    #pragma unroll
    for (int mt = 0; mt < 4; mt++) {
        #pragma unroll
        for (int r = 0; r < 4; r++) {
            int o = o0 + 64 * wm + 16 * mt + qd * 4 + r;
            float bb = bo[o];
            #pragma unroll
            for (int nt = 0; nt < 4; nt++) {
                int i = i0t + 64 * wn + 16 * nt + nn;
                size_t idx = ((size_t)b * C + o) * HW + i;
                out[idx] = acc[mt][nt][r] + bb + x[idx];
            }
        }
    }
}

extern "C" void kernel_launch(void* const* d_in, const int* in_sizes, int n_in,
                              void* d_out, int out_size, void* d_ws, size_t ws_size,
                              hipStream_t stream) {
    const float* x    = (const float*)d_in[0];
    const float* gn_w = (const float*)d_in[1];
    const float* gn_b = (const float*)d_in[2];
    const float* wq   = (const float*)d_in[3];
    const float* bq   = (const float*)d_in[4];
    const float* wk   = (const float*)d_in[5];
    const float* bk   = (const float*)d_in[6];
    const float* wv   = (const float*)d_in[7];
    const float* bv   = (const float*)d_in[8];
    const float* wo   = (const float*)d_in[9];
    const float* bo   = (const float*)d_in[10];
    float* out = (float*)d_out;

    const size_t WSZ = (size_t)C * C;        // 262144
    const size_t S1  = (size_t)B * C * HW;   // 8,388,608
    u16* wb    = (u16*)d_ws;                 // [q,k,v,o] bf16 weights
    u16* wob   = wb + 3 * WSZ;
    u16* xnT   = wob + WSZ;                  // dead after qkv; oT aliases it
    u16* oT    = xnT;
    u16* qT    = xnT + S1;
    u16* kT    = qT + S1;
    u16* vimg  = kT + S1;
    u16* Opart = vimg + S1;                  // 2*S1 bf16 partials
    float2* ml = (float2*)(Opart + 2 * S1);  // 2*B*HW float2

    hipLaunchKernelGGL(conv_kernel,  dim3(256, 4), dim3(256), 0, stream, wq, wk, wv, wo, wb);
    hipLaunchKernelGGL(gn_kernel,    dim3(B*NG), dim3(256), 0, stream, x, gn_w, gn_b, xnT);
    hipLaunchKernelGGL(qkv_kernel,   dim3(HW/128, 12, B), dim3(256), 0, stream,
                       xnT, wb, bq, bk, bv, qT, kT, vimg);
    hipLaunchKernelGGL(attn_kernel,  dim3(HW/32, B, 2), dim3(256), 0, stream,
                       qT, kT, vimg, Opart, ml);
    hipLaunchKernelGGL(merge_kernel, dim3(B*HW/4), dim3(256), 0, stream, Opart, ml, oT);
    hipLaunchKernelGGL(proj_kernel,  dim3(HW/128, C/128, B), dim3(256), 0, stream, oT, wob, bo, x, out);
}

// Round 7
// 470.268 us; speedup vs baseline: 3.0353x; 1.2232x over previous
//
#include <hip/hip_runtime.h>

#define B 4
#define C 512
#define HW 4096
#define NG 32
#define GSZ 65536   // (C/NG)*HW = 16*4096

typedef unsigned short u16;
typedef unsigned int u32;
typedef __attribute__((ext_vector_type(8))) short short8;
typedef __attribute__((ext_vector_type(4))) float f32x4;

__device__ __forceinline__ float bf2f(u16 u) {
    union { u32 i; float f; } x; x.i = ((u32)u) << 16; return x.f;
}
__device__ __forceinline__ u16 f2bf(float f) {
    union { u32 i; float f; } x; x.f = f;
    u32 r = x.i + 0x7FFF + ((x.i >> 16) & 1);   // round-nearest-even
    return (u16)(r >> 16);
}

// async global->LDS, 16B per lane. LDS dest = wave-uniform base + lane*16.
__device__ __forceinline__ void gld16(const u16* g, u16* l) {
    __builtin_amdgcn_global_load_lds(
        (const __attribute__((address_space(1))) void*)g,
        (__attribute__((address_space(3))) void*)l, 16, 0, 0);
}

// ---------------- Kernel 0: fp32 -> bf16 weight conversion ----------------
__global__ __launch_bounds__(256) void conv_kernel(
        const float* __restrict__ wq, const float* __restrict__ wk,
        const float* __restrict__ wv, const float* __restrict__ wo,
        u16* __restrict__ dst) {
    const int mat = blockIdx.y;
    const float* src = (mat == 0) ? wq : (mat == 1) ? wk : (mat == 2) ? wv : wo;
    const int idx = (blockIdx.x * 256 + threadIdx.x) * 4;
    float4 v = *(const float4*)(src + idx);
    ushort4 r;
    r.x = f2bf(v.x); r.y = f2bf(v.y); r.z = f2bf(v.z); r.w = f2bf(v.w);
    *(ushort4*)(dst + (size_t)mat * (C * C) + idx) = r;
}

// ---------------- Kernel 1: GroupNorm -> bf16 xnT (b, hw, c) ----------------
__global__ __launch_bounds__(256) void gn_kernel(
        const float* __restrict__ x, const float* __restrict__ gamma,
        const float* __restrict__ beta, u16* __restrict__ xnT) {
    const int gl = blockIdx.x;                // b*32 + g
    const int b = gl >> 5, g = gl & 31;
    const size_t base = (size_t)gl * GSZ;
    const int tid = threadIdx.x;
    float s = 0.f, s2 = 0.f;
    for (int i = tid * 4; i < GSZ; i += 1024) {
        float4 v4 = *(const float4*)(x + base + i);
        s  += v4.x + v4.y + v4.z + v4.w;
        s2 += v4.x*v4.x + v4.y*v4.y + v4.z*v4.z + v4.w*v4.w;
    }
    #pragma unroll
    for (int off = 32; off > 0; off >>= 1) {
        s  += __shfl_down(s, off, 64);
        s2 += __shfl_down(s2, off, 64);
    }
    __shared__ float rs[4], rs2[4], bc[2];
    int lane = tid & 63, wid = tid >> 6;
    if (lane == 0) { rs[wid] = s; rs2[wid] = s2; }
    __syncthreads();
    if (tid == 0) {
        float ts  = rs[0] + rs[1] + rs[2] + rs[3];
        float ts2 = rs2[0] + rs2[1] + rs2[2] + rs2[3];
        float mean = ts * (1.f / GSZ);
        float var  = ts2 * (1.f / GSZ) - mean * mean;
        bc[0] = mean; bc[1] = rsqrtf(var + 1e-6f);
    }
    __syncthreads();
    const float mean = bc[0], rstd = bc[1];
    const int c0 = g * 16;
    float gm[16], bt[16];
    #pragma unroll
    for (int c = 0; c < 16; c++) {
        float gg = gamma[c0 + c] * rstd;
        gm[c] = gg;
        bt[c] = beta[c0 + c] - mean * gg;
    }
    for (int i = tid; i < HW; i += 256) {
        u32 pk[8];
        #pragma unroll
        for (int c = 0; c < 16; c += 2) {
            float a0 = x[base + (size_t)c * HW + i] * gm[c] + bt[c];
            float a1 = x[base + (size_t)(c + 1) * HW + i] * gm[c + 1] + bt[c + 1];
            pk[c >> 1] = (u32)f2bf(a0) | ((u32)f2bf(a1) << 16);
        }
        u16* dst = xnT + ((size_t)b * HW + i) * C + c0;
        *(uint4*)dst       = make_uint4(pk[0], pk[1], pk[2], pk[3]);
        *(uint4*)(dst + 8) = make_uint4(pk[4], pk[5], pk[6], pk[7]);
    }
}

// ---------------- Kernel 2: MFMA QKV projection ----------------
// A = xnT (m=i, k=c contig), B = W (n=o, k=c contig) -> D[i,o]
// q/k: store qT/kT (b,hw,c);  v: store vimg swizzled chunks (ushort4 runs)
__global__ __launch_bounds__(256) void qkv_kernel(
        const u16* __restrict__ xnT, const u16* __restrict__ wb,
        const float* __restrict__ bq, const float* __restrict__ bk,
        const float* __restrict__ bv,
        u16* __restrict__ qT, u16* __restrict__ kT, u16* __restrict__ vimg) {
    const int mat = blockIdx.y >> 2;
    const int oT0 = (blockIdx.y & 3) * 128;
    const int iT0 = blockIdx.x * 128;
    const int b = blockIdx.z;
    const u16* Ag = xnT + ((size_t)b * HW + iT0) * C;
    const u16* Bg = wb + (size_t)mat * C * C + (size_t)oT0 * C;
    const float* bias = (mat == 0) ? bq : (mat == 1) ? bk : bv;

    const int tid = threadIdx.x;
    const int w = tid >> 6, lane = tid & 63;
    const int qd = lane >> 4, nn = lane & 15;
    const int wm = w & 1, wn = w >> 1;

    __shared__ __align__(16) u16 As[2][128 * 32];
    __shared__ __align__(16) u16 Bs[2][128 * 32];

    f32x4 acc[4][4];
    #pragma unroll
    for (int mt = 0; mt < 4; mt++)
        #pragma unroll
        for (int nt = 0; nt < 4; nt++) acc[mt][nt] = (f32x4){0.f, 0.f, 0.f, 0.f};

    auto stage = [&](u16* dst, const u16* g, int c0) {
        #pragma unroll
        for (int p = 0; p < 2; p++) {
            int rbase = 32 * w + 16 * p;
            int row = rbase + (lane >> 2);
            gld16(g + (size_t)row * C + c0 + (((lane & 3) ^ ((row >> 1) & 3)) << 3),
                  dst + rbase * 32);
        }
    };

    stage(As[0], Ag, 0);
    stage(Bs[0], Bg, 0);

    for (int kt = 0; kt < 16; kt++) {
        const int cur = kt & 1;
        __syncthreads();
        if (kt < 15) {
            stage(As[cur ^ 1], Ag, (kt + 1) * 32);
            stage(Bs[cur ^ 1], Bg, (kt + 1) * 32);
        }
        short8 af[4], bf[4];
        #pragma unroll
        for (int mt = 0; mt < 4; mt++) {
            int row = 64 * wm + 16 * mt + nn;
            af[mt] = *(const short8*)&As[cur][row * 32 + ((qd ^ ((row >> 1) & 3)) << 3)];
        }
        #pragma unroll
        for (int nt = 0; nt < 4; nt++) {
            int row = 64 * wn + 16 * nt + nn;
            bf[nt] = *(const short8*)&Bs[cur][row * 32 + ((qd ^ ((row >> 1) & 3)) << 3)];
        }
        #pragma unroll
        for (int mt = 0; mt < 4; mt++)
            #pragma unroll
            for (int nt = 0; nt < 4; nt++)
                acc[mt][nt] = __builtin_amdgcn_mfma_f32_16x16x32_bf16(af[mt], bf[nt], acc[mt][nt], 0, 0, 0);
    }

    if (mat < 2) {
        u16* dstT = ((mat == 0) ? qT : kT) + (size_t)b * HW * C;
        #pragma unroll
        for (int nt = 0; nt < 4; nt++) {
            int o = oT0 + 64 * wn + 16 * nt + nn;
            float bb = bias[o];
            #pragma unroll
            for (int mt = 0; mt < 4; mt++) {
                int ib = iT0 + 64 * wm + 16 * mt + qd * 4;
                u16* p = dstT + (size_t)ib * C + o;
                p[0]     = f2bf(acc[mt][nt][0] + bb);
                p[C]     = f2bf(acc[mt][nt][1] + bb);
                p[2 * C] = f2bf(acc[mt][nt][2] + bb);
                p[3 * C] = f2bf(acc[mt][nt][3] + bb);
            }
        }
    } else {
        u16* vb = vimg + (size_t)b * 128 * 16384;
        #pragma unroll
        for (int nt = 0; nt < 4; nt++) {
            int c = oT0 + 64 * wn + 16 * nt + nn;
            float bb = bias[c];
            #pragma unroll
            for (int mt = 0; mt < 4; mt++) {
                int ib = iT0 + 64 * wm + 16 * mt + qd * 4;
                int ch = ib >> 5;
                int j0 = ib & 31;
                ushort4 st;
                st.x = f2bf(acc[mt][nt][0] + bb);
                st.y = f2bf(acc[mt][nt][1] + bb);
                st.z = f2bf(acc[mt][nt][2] + bb);
                st.w = f2bf(acc[mt][nt][3] + bb);
                *(ushort4*)&vb[(size_t)ch * 16384 + c * 32 +
                               (((j0 >> 3) ^ ((c >> 2) & 3)) << 3) + (j0 & 7)] = st;
            }
        }
    }
}

// ---------------- Kernel 3: MFMA flash attention (32-row tiles, j-split halves) ----------------
// Block: 32 q-rows, 4 waves, 256 thr. blockIdx.z = j-half (2048 j each).
// Wave w = (row-half rw = w&1) x (j-quadrant jh = w>>1) for the 32x32 S tile.
// PV: wave w owns cols [128w, 128w+128) for all 32 rows -> oacc 64 f32/lane.
// Deferred block-scalar max: p = exp(s - mreg); mreg updated via LDS flags,
// applied post-PV (exact). 2 barriers/chunk.
__global__ __launch_bounds__(256, 2) void attn_kernel(
        const u16* __restrict__ qT, const u16* __restrict__ kT,
        const u16* __restrict__ vimg, u16* __restrict__ Opart,
        float2* __restrict__ mlpart) {
    const int b = blockIdx.y;
    const int i0 = blockIdx.x * 32;
    const int h = blockIdx.z;          // j-half
    const int tid = threadIdx.x;
    const int w = tid >> 6;
    const int lane = tid & 63;
    const int q = lane >> 4;
    const int n = lane & 15;
    const int rw = w & 1;              // S row-half
    const int jh = w >> 1;             // S j-quadrant

    __shared__ __align__(16) u16 kbuf[32 * 512];   // 32 KB, XOR-chunk swizzle
    __shared__ __align__(16) u16 vbuf[16384];      // 32 KB, vimg image
    __shared__ __align__(16) u16 pbuf[32 * 40];    // 2.5 KB
    __shared__ __align__(16) float mflag[4];
    __shared__ __align__(16) float lpart[2][32];

    // persistent Q A-fragments: rows i0 + rw*16 + n, k = kk*32 + q*8 .. +7
    short8 qf[16];
    {
        const u16* qrow = qT + ((size_t)b * HW + i0 + rw * 16 + n) * C + q * 8;
        #pragma unroll
        for (int k = 0; k < 16; k++) {
            uint4 u = *(const uint4*)(qrow + k * 32);
            qf[k] = *(const short8*)&u;
        }
    }
    f32x4 oacc[2][8];
    #pragma unroll
    for (int mt = 0; mt < 2; mt++)
        #pragma unroll
        for (int nt = 0; nt < 8; nt++)
            oacc[mt][nt] = (f32x4){0.f, 0.f, 0.f, 0.f};
    float mreg = 0.f;                  // block-uniform running max (lockstep)
    float lsum[4] = {0.f, 0.f, 0.f, 0.f};

    const u16* kTb = kT + (size_t)b * HW * C;
    const u16* vTb = vimg + (size_t)b * 128 * 16384;

    // K row j (0..31): phys 16B-chunk l holds logical chunk (l ^ (j&7))
    auto stageK = [&](int gc) {
        const u16* gk = kTb + (size_t)gc * 32 * C;
        #pragma unroll
        for (int ii = 0; ii < 8; ii++) {
            int j = w * 8 + ii;
            gld16(gk + (size_t)j * C + ((lane ^ (j & 7)) << 3), &kbuf[j * 512]);
        }
    };
    auto stageV = [&](int gc) {
        const u16* gv = vTb + (size_t)gc * 16384;
        #pragma unroll
        for (int ii = 0; ii < 8; ii++) {
            int tt = w * 8 + ii;
            gld16(gv + tt * 512 + lane * 8, &vbuf[tt * 512]);
        }
    };

    const int gc0 = h * 64;
    stageK(gc0);
    stageV(gc0);
    const float scale = 0.04419417382415922f;   // 512^-0.5
    __syncthreads();   // chunk 0 staged

    #pragma unroll 1
    for (int t = 0; t < 64; ++t) {
        // ---- S quadrant = Q(rows rw*16..) K^T(j = jh*16 + n), 2 chains ----
        f32x4 sa = {0.f, 0.f, 0.f, 0.f}, sb = {0.f, 0.f, 0.f, 0.f};
        {
            const int sw = n & 7;
            const u16* kb = kbuf + (jh * 16 + n) * 512;
            #pragma unroll
            for (int kk = 0; kk < 8; kk++) {
                short8 bfa = *(const short8*)&kb[(((2 * kk) * 4 + q) ^ sw) << 3];
                short8 bfb = *(const short8*)&kb[(((2 * kk + 1) * 4 + q) ^ sw) << 3];
                sa = __builtin_amdgcn_mfma_f32_16x16x32_bf16(qf[2 * kk], bfa, sa, 0, 0, 0);
                sb = __builtin_amdgcn_mfma_f32_16x16x32_bf16(qf[2 * kk + 1], bfb, sb, 0, 0, 0);
            }
        }
        float sv[4];
        #pragma unroll
        for (int r = 0; r < 4; r++) sv[r] = (sa[r] + sb[r]) * scale;
        // ---- p = exp(s - mreg); exceedance flag (rare path does the reduce) ----
        float pm = fmaxf(fmaxf(sv[0], sv[1]), fmaxf(sv[2], sv[3]));
        float flagv = -1e30f;
        if (__any(pm > mreg + 1.0f)) {
            float mx = pm;
            mx = fmaxf(mx, __shfl_xor(mx, 1));
            mx = fmaxf(mx, __shfl_xor(mx, 2));
            mx = fmaxf(mx, __shfl_xor(mx, 4));
            mx = fmaxf(mx, __shfl_xor(mx, 8));
            mx = fmaxf(mx, __shfl_xor(mx, 16));
            mx = fmaxf(mx, __shfl_xor(mx, 32));
            flagv = mx;
        }
        if (lane == 0) mflag[w] = flagv;
        #pragma unroll
        for (int r = 0; r < 4; r++) {
            float p = __expf(sv[r] - mreg);
            lsum[r] += p;
            pbuf[(rw * 16 + q * 4 + r) * 40 + jh * 16 + n] = f2bf(p);
        }
        __syncthreads();   // B2: pbuf/flags visible; kbuf consumed
        if (t < 63) stageK(gc0 + t + 1);   // overlaps PV; drained at B3
        f32x4 fl = *(const f32x4*)mflag;   // broadcast read
        float mnew = fmaxf(fmaxf(mreg, fl[0]), fmaxf(fmaxf(fl[1], fl[2]), fl[3]));
        // ---- O += P V  (wave w: cols 128w..128w+127, all 32 rows) ----
        short8 pf[2];
        #pragma unroll
        for (int mt = 0; mt < 2; mt++)
            pf[mt] = *(const short8*)&pbuf[(mt * 16 + n) * 40 + q * 8];
        #pragma unroll
        for (int nt = 0; nt < 8; nt++) {
            int c = w * 128 + nt * 16 + n;
            short8 vf = *(const short8*)&vbuf[c * 32 + ((q ^ ((c >> 2) & 3)) << 3)];
            #pragma unroll
            for (int mt = 0; mt < 2; mt++)
                oacc[mt][nt] = __builtin_amdgcn_mfma_f32_16x16x32_bf16(pf[mt], vf, oacc[mt][nt], 0, 0, 0);
        }
        // ---- rare deferred rescale (exact: this chunk added at old scale) ----
        if (mnew > mreg) {
            float al = __expf(mreg - mnew);
            #pragma unroll
            for (int mt = 0; mt < 2; mt++)
                #pragma unroll
                for (int nt = 0; nt < 8; nt++) {
                    oacc[mt][nt][0] *= al; oacc[mt][nt][1] *= al;
                    oacc[mt][nt][2] *= al; oacc[mt][nt][3] *= al;
                }
            #pragma unroll
            for (int r = 0; r < 4; r++) lsum[r] *= al;
            mreg = mnew;
        }
        __syncthreads();   // B3: vbuf consumed; stageK drained
        if (t < 63) stageV(gc0 + t + 1);   // drained at B2 of t+1
    }
    // ---- epilogue: per-(row,jh) partial l -> LDS; merge; write partials ----
    #pragma unroll
    for (int r = 0; r < 4; r++) {
        float l = lsum[r];
        l += __shfl_xor(l, 1);
        l += __shfl_xor(l, 2);
        l += __shfl_xor(l, 4);
        l += __shfl_xor(l, 8);
        if (n == 0) lpart[jh][rw * 16 + q * 4 + r] = l;
    }
    __syncthreads();
    if (jh == 0 && n == 0) {
        #pragma unroll
        for (int r = 0; r < 4; r++) {
            int row = rw * 16 + q * 4 + r;
            float2 e; e.x = mreg; e.y = lpart[0][row] + lpart[1][row];
            mlpart[((size_t)h * B + b) * HW + i0 + row] = e;
        }
    }
    #pragma unroll
    for (int mt = 0; mt < 2; mt++) {
        float inv[4];
        #pragma unroll
        for (int r = 0; r < 4; r++) {
            int row = mt * 16 + q * 4 + r;
            inv[r] = 1.f / (lpart[0][row] + lpart[1][row]);
        }
        #pragma unroll
        for (int nt = 0; nt < 8; nt++) {
            int cc = w * 128 + nt * 16 + n;
            size_t base = (((size_t)h * B + b) * HW + i0 + mt * 16 + q * 4) * C + cc;
            Opart[base        ] = f2bf(oacc[mt][nt][0] * inv[0]);
            Opart[base +   C  ] = f2bf(oacc[mt][nt][1] * inv[1]);
            Opart[base + 2 * C] = f2bf(oacc[mt][nt][2] * inv[2]);
            Opart[base + 3 * C] = f2bf(oacc[mt][nt][3] * inv[3]);
        }
    }
}

// ---------------- Kernel 3b: merge the two j-half partials ----------------
__global__ __launch_bounds__(256) void merge_kernel(
        const u16* __restrict__ Opart, const float2* __restrict__ mlpart,
        u16* __restrict__ oT) {
    const int row = blockIdx.x * 4 + (threadIdx.x >> 6);   // b*HW + i
    const int lane = threadIdx.x & 63;
    float2 e0 = mlpart[row];
    float2 e1 = mlpart[(size_t)B * HW + row];
    float m = fmaxf(e0.x, e1.x);
    float a0 = __expf(e0.x - m) * e0.y;
    float a1 = __expf(e1.x - m) * e1.y;
    float inv = 1.f / (a0 + a1);
    a0 *= inv; a1 *= inv;
    size_t off = (size_t)row * C + lane * 8;
    uint4 u0 = *(const uint4*)(Opart + off);
    uint4 u1 = *(const uint4*)(Opart + (size_t)B * HW * C + off);
    const u32* p0 = (const u32*)&u0;
    const u32* p1 = (const u32*)&u1;
    u32 s[4];
    #pragma unroll
    for (int k = 0; k < 4; k++) {
        u16 lo = f2bf(a0 * bf2f((u16)p0[k]) + a1 * bf2f((u16)p1[k]));
        u16 hi = f2bf(a0 * bf2f((u16)(p0[k] >> 16)) + a1 * bf2f((u16)(p1[k] >> 16)));
        s[k] = (u32)lo | ((u32)hi << 16);
    }
    *(uint4*)(oT + off) = make_uint4(s[0], s[1], s[2], s[3]);
}

// ---------------- Kernel 4: MFMA output projection + bias + residual ----------------
// A = wo (m=o, k=c), B = oT (n=i, k=c) -> D[o,i] (c-major output)
__global__ __launch_bounds__(256) void proj_kernel(
        const u16* __restrict__ oT, const u16* __restrict__ wob,
        const float* __restrict__ bo, const float* __restrict__ x,
        float* __restrict__ out) {
    const int o0 = blockIdx.y * 128;
    const int i0t = blockIdx.x * 128;
    const int b = blockIdx.z;
    const u16* Ag = wob + (size_t)o0 * C;
    const u16* Bg = oT + ((size_t)b * HW + i0t) * C;

    const int tid = threadIdx.x;
    const int w = tid >> 6, lane = tid & 63;
    const int qd = lane >> 4, nn = lane & 15;
    const int wm = w & 1, wn = w >> 1;

    __shared__ __align__(16) u16 As[2][128 * 32];
    __shared__ __align__(16) u16 Bs[2][128 * 32];

    f32x4 acc[4][4];
    #pragma unroll
    for (int mt = 0; mt < 4; mt++)
        #pragma unroll
        for (int nt = 0; nt < 4; nt++) acc[mt][nt] = (f32x4){0.f, 0.f, 0.f, 0.f};

    auto stage = [&](u16* dst, const u16* g, int c0) {
        #pragma unroll
        for (int p = 0; p < 2; p++) {
            int rbase = 32 * w + 16 * p;
            int row = rbase + (lane >> 2);
            gld16(g + (size_t)row * C + c0 + (((lane & 3) ^ ((row >> 1) & 3)) << 3),
                  dst + rbase * 32);
        }
    };

    stage(As[0], Ag, 0);
    stage(Bs[0], Bg, 0);

    for (int kt = 0; kt < 16; kt++) {
        const int cur = kt & 1;
        __syncthreads();
        if (kt < 15) {
            stage(As[cur ^ 1], Ag, (kt + 1) * 32);
            stage(Bs[cur ^ 1], Bg, (kt + 1) * 32);
        }
        short8 af[4], bf[4];
        #pragma unroll
        for (int mt = 0; mt < 4; mt++) {
            int row = 64 * wm + 16 * mt + nn;
            af[mt] = *(const short8*)&As[cur][row * 32 + ((qd ^ ((row >> 1) & 3)) << 3)];
        }
        #pragma unroll
        for (int nt = 0; nt < 4; nt++) {
            int row = 64 * wn + 16 * nt + nn;
            bf[nt] = *(const short8*)&Bs[cur][row * 32 + ((qd ^ ((row >> 1) & 3)) << 3)];
        }
        #pragma unroll
        for (int mt = 0; mt < 4; mt++)
            #pragma unroll
            for (int nt = 0; nt < 4; nt++)
                acc[mt][nt] = __builtin_amdgcn_mfma_f32_16x16x32_bf16(af[mt], bf[nt], acc[mt][nt], 0, 0, 0);
    }

    #pragma unroll
    for (int mt = 0; mt < 4; mt++) {
        #pragma unroll
        for (int r = 0; r < 4; r++) {
            int o = o0 + 64 * wm + 16 * mt + qd * 4 + r;
            float bb = bo[o];
            #pragma unroll
            for (int nt = 0; nt < 4; nt++) {
                int i = i0t + 64 * wn + 16 * nt + nn;
                size_t idx = ((size_t)b * C + o) * HW + i;
                out[idx] = acc[mt][nt][r] + bb + x[idx];
            }
        }
    }
}

extern "C" void kernel_launch(void* const* d_in, const int* in_sizes, int n_in,
                              void* d_out, int out_size, void* d_ws, size_t ws_size,
                              hipStream_t stream) {
    const float* x    = (const float*)d_in[0];
    const float* gn_w = (const float*)d_in[1];
    const float* gn_b = (const float*)d_in[2];
    const float* wq   = (const float*)d_in[3];
    const float* bq   = (const float*)d_in[4];
    const float* wk   = (const float*)d_in[5];
    const float* bk   = (const float*)d_in[6];
    const float* wv   = (const float*)d_in[7];
    const float* bv   = (const float*)d_in[8];
    const float* wo   = (const float*)d_in[9];
    const float* bo   = (const float*)d_in[10];
    float* out = (float*)d_out;

    const size_t WSZ = (size_t)C * C;        // 262144
    const size_t S1  = (size_t)B * C * HW;   // 8,388,608
    u16* wb    = (u16*)d_ws;                 // [q,k,v,o] bf16 weights
    u16* wob   = wb + 3 * WSZ;
    u16* xnT   = wob + WSZ;                  // dead after qkv; oT aliases it
    u16* oT    = xnT;
    u16* qT    = xnT + S1;
    u16* kT    = qT + S1;
    u16* vimg  = kT + S1;
    u16* Opart = vimg + S1;                  // 2*S1 bf16 partials
    float2* ml = (float2*)(Opart + 2 * S1);  // 2*B*HW float2

    hipLaunchKernelGGL(conv_kernel,  dim3(256, 4), dim3(256), 0, stream, wq, wk, wv, wo, wb);
    hipLaunchKernelGGL(gn_kernel,    dim3(B*NG), dim3(256), 0, stream, x, gn_w, gn_b, xnT);
    hipLaunchKernelGGL(qkv_kernel,   dim3(HW/128, 12, B), dim3(256), 0, stream,
                       xnT, wb, bq, bk, bv, qT, kT, vimg);
    hipLaunchKernelGGL(attn_kernel,  dim3(HW/32, B, 2), dim3(256), 0, stream,
                       qT, kT, vimg, Opart, ml);
    hipLaunchKernelGGL(merge_kernel, dim3(B*HW/4), dim3(256), 0, stream, Opart, ml, oT);
    hipLaunchKernelGGL(proj_kernel,  dim3(HW/128, C/128, B), dim3(256), 0, stream, oT, wob, bo, x, out);
}